// Round 1
// baseline (1181.875 us; speedup 1.0000x reference)
//
#include <hip/hip_runtime.h>
#include <math.h>

#define B_   8
#define C_   256
#define S_   1024
#define H_   8
#define DH_  32
#define M_   8192    // B_*S_
#define HID_ 1024
#define NELT 2097152 // B_*C_*S_

// ---------------- reduction helpers ----------------
__device__ __forceinline__ float waveReduceSum(float v) {
#pragma unroll
  for (int off = 32; off > 0; off >>= 1) v += __shfl_xor(v, off);
  return v;
}
__device__ __forceinline__ float waveReduceMax(float v) {
#pragma unroll
  for (int off = 32; off > 0; off >>= 1) v = fmaxf(v, __shfl_xor(v, off));
  return v;
}

// ---------------- LayerNorm (optionally reading x transposed) ----------------
// TRANSPOSED=1: input is x[b][c][s], row = b*S+si, we read x[b][c][si] and also
// write the plain transpose t. TRANSPOSED=0: input is t[row][c] directly.
template <int TRANSPOSED>
__global__ __launch_bounds__(256) void ln_kernel(const float* __restrict__ in,
                                                 const float* __restrict__ g,
                                                 const float* __restrict__ bta,
                                                 float* __restrict__ t,
                                                 float* __restrict__ tn) {
  __shared__ float s1s[4], s2s[4];
  int row = blockIdx.x;  // b*S + si
  int c = threadIdx.x;
  float v;
  if (TRANSPOSED) {
    int b = row >> 10, si = row & 1023;
    v = in[(((size_t)b * C_ + c) << 10) + si];
  } else {
    v = in[(size_t)row * C_ + c];
  }
  float s1 = waveReduceSum(v);
  float s2 = waveReduceSum(v * v);
  int wave = threadIdx.x >> 6;
  if ((threadIdx.x & 63) == 0) { s1s[wave] = s1; s2s[wave] = s2; }
  __syncthreads();
  s1 = s1s[0] + s1s[1] + s1s[2] + s1s[3];
  s2 = s2s[0] + s2s[1] + s2s[2] + s2s[3];
  float mu = s1 * (1.0f / 256.0f);
  float var = s2 * (1.0f / 256.0f) - mu * mu;
  float rs = rsqrtf(var + 1e-5f);
  size_t o = (size_t)row * C_ + c;
  if (TRANSPOSED) t[o] = v;
  tn[o] = (v - mu) * rs * g[c] + bta[c];
}

// ---------------- generic f32 GEMM: C = act(A @ W^T + bias) (+ res) ----------
// A: [M,K] row-major; W: [N,K] row-major; tile 64x64x32, 4x4 per thread.
// w_bstride: if nonzero, W += (m0/rows_per_batch)*w_bstride (per-batch weights)
__device__ __forceinline__ float gelu_exact(float v) {
  return 0.5f * v * (1.0f + erff(v * 0.70710678118654752f));
}

template <int ACT>  // 0 = none, 1 = exact gelu
__global__ __launch_bounds__(256) void gemm64(const float* __restrict__ A,
                                              const float* __restrict__ W,
                                              const float* __restrict__ bias,
                                              const float* __restrict__ res,
                                              float* __restrict__ Cout, int M,
                                              int Nn, int K, int w_bstride,
                                              int rows_per_batch) {
  __shared__ float As[32][68];
  __shared__ float Ws[32][68];
  int tid = threadIdx.x;
  int n0 = blockIdx.x * 64;
  int m0 = blockIdx.y * 64;
  const float* Wb = W;
  if (w_bstride) Wb += (size_t)(m0 / rows_per_batch) * w_bstride;
  float acc[4][4] = {};
  int tx = tid & 15, ty = tid >> 4;
  int lr = tid >> 3;         // 0..31
  int lk = (tid & 7) * 4;    // 0,4,...,28

  for (int k0 = 0; k0 < K; k0 += 32) {
    __syncthreads();
#pragma unroll
    for (int h = 0; h < 2; ++h) {
      int mm = lr + h * 32;
      float4 av = *(const float4*)&A[(size_t)(m0 + mm) * K + k0 + lk];
      As[lk + 0][mm] = av.x; As[lk + 1][mm] = av.y;
      As[lk + 2][mm] = av.z; As[lk + 3][mm] = av.w;
      float4 wv = *(const float4*)&Wb[(size_t)(n0 + mm) * K + k0 + lk];
      Ws[lk + 0][mm] = wv.x; Ws[lk + 1][mm] = wv.y;
      Ws[lk + 2][mm] = wv.z; Ws[lk + 3][mm] = wv.w;
    }
    __syncthreads();
#pragma unroll
    for (int kk = 0; kk < 32; ++kk) {
      float4 a4 = *(const float4*)&As[kk][ty * 4];
      float4 b4 = *(const float4*)&Ws[kk][tx * 4];
      float av[4] = {a4.x, a4.y, a4.z, a4.w};
      float bv[4] = {b4.x, b4.y, b4.z, b4.w};
#pragma unroll
      for (int i = 0; i < 4; ++i)
#pragma unroll
        for (int j = 0; j < 4; ++j) acc[i][j] += av[i] * bv[j];
    }
  }
#pragma unroll
  for (int i = 0; i < 4; ++i) {
    int mrow = m0 + ty * 4 + i;
#pragma unroll
    for (int j = 0; j < 4; ++j) {
      int ncol = n0 + tx * 4 + j;
      float v = acc[i][j];
      if (bias) v += bias[ncol];
      if (ACT == 1) v = gelu_exact(v);
      if (res) v += res[(size_t)mrow * Nn + ncol];
      Cout[(size_t)mrow * Nn + ncol] = v;
    }
  }
}

// ---------------- flash attention (f32) ----------------
// qkv: [B,S,768]; o: [B,S,256]. 4 waves/block, 8 q-rows/wave, 64-key tiles.
__global__ __launch_bounds__(256) void attn_kernel(const float* __restrict__ qkv,
                                                   float* __restrict__ o) {
  __shared__ float Q[32][36];
  __shared__ float Kt[64][36];
  __shared__ float Vt[64][33];
  __shared__ float P[4][64];
  int blk = blockIdx.x;       // 8*8*32
  int rowblk = blk & 31;
  int bh = blk >> 5;
  int hh = bh & 7;
  int b = bh >> 3;
  int tid = threadIdx.x;
  int wave = tid >> 6, lane = tid & 63;
  int half = lane >> 5, d = lane & 31;
  int r0 = rowblk * 32;
  const float* base = qkv + (size_t)b * S_ * 768 + hh * 32;

  for (int i = tid; i < 32 * 32; i += 256) {
    int rr = i >> 5, dd = i & 31;
    Q[rr][dd] = base[(size_t)(r0 + rr) * 768 + dd];
  }
  float m[8], l[8], acc[8];
#pragma unroll
  for (int r = 0; r < 8; ++r) { m[r] = -1e30f; l[r] = 0.f; acc[r] = 0.f; }
  const float scale = 0.17677669529663687f;  // 1/sqrt(32)

  for (int kb = 0; kb < 16; ++kb) {
    __syncthreads();
    for (int i = tid; i < 64 * 32; i += 256) {
      int kk = i >> 5, dd = i & 31;
      const float* kr = base + (size_t)(kb * 64 + kk) * 768 + dd;
      Kt[kk][dd] = kr[256];
      Vt[kk][dd] = kr[512];
    }
    __syncthreads();
    float4 kreg[8];
#pragma unroll
    for (int dq = 0; dq < 8; ++dq) kreg[dq] = *(const float4*)&Kt[lane][dq * 4];
    float vreg[32];
#pragma unroll
    for (int kk = 0; kk < 32; ++kk) vreg[kk] = Vt[half * 32 + kk][d];
#pragma unroll
    for (int r = 0; r < 8; ++r) {
      int qr = wave * 8 + r;
      float sc = 0.f;
#pragma unroll
      for (int dq = 0; dq < 8; ++dq) {
        float4 q4 = *(const float4*)&Q[qr][dq * 4];
        sc += q4.x * kreg[dq].x + q4.y * kreg[dq].y +
              q4.z * kreg[dq].z + q4.w * kreg[dq].w;
      }
      sc *= scale;
      float mx = waveReduceMax(sc);
      float mnew = fmaxf(m[r], mx);
      float p = __expf(sc - mnew);
      float corr = __expf(m[r] - mnew);
      m[r] = mnew;
      float ps = waveReduceSum(p);
      l[r] = l[r] * corr + ps;
      P[wave][lane] = p;  // wave-lockstep LDS exchange (no barrier needed)
      float a0 = acc[r] * corr;
#pragma unroll
      for (int k4 = 0; k4 < 8; ++k4) {
        float4 p4 = *(const float4*)&P[wave][half * 32 + k4 * 4];
        a0 += p4.x * vreg[k4 * 4 + 0] + p4.y * vreg[k4 * 4 + 1] +
              p4.z * vreg[k4 * 4 + 2] + p4.w * vreg[k4 * 4 + 3];
      }
      acc[r] = a0;
    }
  }
#pragma unroll
  for (int r = 0; r < 8; ++r) {
    float v = acc[r] + __shfl_down(acc[r], 32);
    if (half == 0) {
      o[((size_t)b * S_ + r0 + wave * 8 + r) * C_ + hh * 32 + d] = v / l[r];
    }
  }
}

// ---------------- transpose t3 [b,s,c] -> x2 [b,c,s] ----------------
__global__ __launch_bounds__(256) void transpose_kernel(const float* __restrict__ t,
                                                        float* __restrict__ x2) {
  int idx = blockIdx.x * 256 + threadIdx.x;  // [b][c][s] linear
  int si = idx & 1023;
  int c = (idx >> 10) & 255;
  int b = idx >> 18;
  x2[idx] = t[((size_t)b * S_ + si) * C_ + c];
}

// ---------------- channel scores: a_pre[b][i][j] = sum_s qf[s][i]*kf[s][j] ----
__global__ __launch_bounds__(256) void chan_scores(const float* __restrict__ qf,
                                                   const float* __restrict__ kf,
                                                   float* __restrict__ a_pre) {
  __shared__ float Qs[32][68];
  __shared__ float Ks[32][68];
  int b = blockIdx.z;
  int i0 = blockIdx.y * 64;
  int j0 = blockIdx.x * 64;
  const float* qb = qf + (size_t)b * S_ * C_;
  const float* kb_ = kf + (size_t)b * S_ * C_;
  int tid = threadIdx.x, tx = tid & 15, ty = tid >> 4;
  float acc[4][4] = {};
  for (int s0 = 0; s0 < S_; s0 += 32) {
    __syncthreads();
#pragma unroll
    for (int h = 0; h < 2; ++h) {
      int ss = (tid >> 4) + h * 16;
      int ii = (tid & 15) * 4;
      *(float4*)&Qs[ss][ii] = *(const float4*)&qb[(size_t)(s0 + ss) * C_ + i0 + ii];
      *(float4*)&Ks[ss][ii] = *(const float4*)&kb_[(size_t)(s0 + ss) * C_ + j0 + ii];
    }
    __syncthreads();
#pragma unroll
    for (int ss = 0; ss < 32; ++ss) {
      float4 a4 = *(const float4*)&Qs[ss][ty * 4];
      float4 b4 = *(const float4*)&Ks[ss][tx * 4];
      float av[4] = {a4.x, a4.y, a4.z, a4.w};
      float bv[4] = {b4.x, b4.y, b4.z, b4.w};
#pragma unroll
      for (int i = 0; i < 4; ++i)
#pragma unroll
        for (int j = 0; j < 4; ++j) acc[i][j] += av[i] * bv[j];
    }
  }
#pragma unroll
  for (int i = 0; i < 4; ++i)
#pragma unroll
    for (int j = 0; j < 4; ++j)
      a_pre[((size_t)b * C_ + i0 + ty * 4 + i) * C_ + j0 + tx * 4 + j] = acc[i][j];
}

// ---------------- row softmax over 256 ----------------
__global__ __launch_bounds__(256) void softmax256(float* __restrict__ a) {
  __shared__ float s1s[4];
  int row = blockIdx.x;
  int j = threadIdx.x;
  float v = a[(size_t)row * 256 + j];
  float mx = waveReduceMax(v);
  int wave = threadIdx.x >> 6;
  if ((threadIdx.x & 63) == 0) s1s[wave] = mx;
  __syncthreads();
  mx = fmaxf(fmaxf(s1s[0], s1s[1]), fmaxf(s1s[2], s1s[3]));
  __syncthreads();
  float e = __expf(v - mx);
  float ss = waveReduceSum(e);
  if ((threadIdx.x & 63) == 0) s1s[wave] = ss;
  __syncthreads();
  ss = s1s[0] + s1s[1] + s1s[2] + s1s[3];
  a[(size_t)row * 256 + j] = e / ss;
}

// ---------------- final: out = x2 + 0.1*den + 0.1*(dwconv3x3 + dw_b) --------
__global__ __launch_bounds__(256) void final_kernel(const float* __restrict__ x2,
                                                    const float* __restrict__ den_t,
                                                    const float* __restrict__ dww,
                                                    const float* __restrict__ dwb,
                                                    float* __restrict__ out) {
  int idx = blockIdx.x * 256 + threadIdx.x;  // out[b][c][y][x]
  int s = idx & 1023;
  int c = (idx >> 10) & 255;
  int b = idx >> 18;
  int y = s >> 5, x = s & 31;
  const float* plane = x2 + (size_t)(b * C_ + c) * S_;
  float lsum = 0.f;
#pragma unroll
  for (int dy = -1; dy <= 1; ++dy) {
    int yy = y + dy;
    if (yy < 0 || yy > 31) continue;
#pragma unroll
    for (int dx = -1; dx <= 1; ++dx) {
      int xx = x + dx;
      if (xx < 0 || xx > 31) continue;
      lsum += dww[c * 9 + (dy + 1) * 3 + (dx + 1)] * plane[yy * 32 + xx];
    }
  }
  lsum += dwb[c];
  float den = den_t[((size_t)b * S_ + s) * C_ + c];
  out[idx] = x2[idx] + 0.1f * den + 0.1f * lsum;
}

// =====================================================================
extern "C" void kernel_launch(void* const* d_in, const int* in_sizes, int n_in,
                              void* d_out, int out_size, void* d_ws,
                              size_t ws_size, hipStream_t stream) {
  const float* x     = (const float*)d_in[0];
  const float* ln1_g = (const float*)d_in[1];
  const float* ln1_b = (const float*)d_in[2];
  const float* wqkv  = (const float*)d_in[3];
  const float* bqkv  = (const float*)d_in[4];
  const float* wo    = (const float*)d_in[5];
  const float* bo    = (const float*)d_in[6];
  const float* ln2_g = (const float*)d_in[7];
  const float* ln2_b = (const float*)d_in[8];
  const float* w1    = (const float*)d_in[9];
  const float* b1    = (const float*)d_in[10];
  const float* w2    = (const float*)d_in[11];
  const float* b2    = (const float*)d_in[12];
  const float* c1_w  = (const float*)d_in[13];
  const float* c1_b  = (const float*)d_in[14];
  const float* c2_w  = (const float*)d_in[15];
  const float* c2_b  = (const float*)d_in[16];
  const float* c3_w  = (const float*)d_in[17];
  const float* c3_b  = (const float*)d_in[18];
  const float* dw_w  = (const float*)d_in[19];
  const float* dw_b  = (const float*)d_in[20];
  float* out = (float*)d_out;

  // workspace layout (floats); needs 10*NELT*4 = 84 MB
  float* ws = (float*)d_ws;
  const size_t N = NELT;
  float* t   = ws;            // t -> t2 -> t3 (in place)
  float* tn  = ws + N;        // tn -> tn2
  float* qkv = ws + 2 * N;    // 3N; later qf@2N, kf@3N, vf@4N
  float* obf = ws + 5 * N;    // o; later x2
  float* hdn = ws + 6 * N;    // 4N; later a@6N (0.25N), den_t@7N (N)
  float* qf  = ws + 2 * N;
  float* kf  = ws + 3 * N;
  float* vf  = ws + 4 * N;
  float* x2  = ws + 5 * N;
  float* amat = ws + 6 * N;   // [8,256,256]
  float* den  = ws + 7 * N;   // den_t [b,s,c]

  // 1. transpose + LN1
  ln_kernel<1><<<M_, 256, 0, stream>>>(x, ln1_g, ln1_b, t, tn);
  // 2. qkv = tn @ wqkv^T + bqkv
  gemm64<0><<<dim3(12, 128), 256, 0, stream>>>(tn, wqkv, bqkv, nullptr, qkv,
                                               M_, 768, 256, 0, 1);
  // 3. attention
  attn_kernel<<<2048, 256, 0, stream>>>(qkv, obf);
  // 4. t2 = t + o @ wo^T + bo (in-place on t)
  gemm64<0><<<dim3(4, 128), 256, 0, stream>>>(obf, wo, bo, t, t, M_, 256, 256,
                                              0, 1);
  // 5. tn2 = LN2(t2)
  ln_kernel<0><<<M_, 256, 0, stream>>>(t, ln2_g, ln2_b, nullptr, tn);
  // 6. hdn = gelu(tn2 @ w1^T + b1)
  gemm64<1><<<dim3(16, 128), 256, 0, stream>>>(tn, w1, b1, nullptr, hdn, M_,
                                               HID_, 256, 0, 1);
  // 7. t3 = t2 + hdn @ w2^T + b2 (in-place on t)
  gemm64<0><<<dim3(4, 128), 256, 0, stream>>>(hdn, w2, b2, t, t, M_, 256,
                                              HID_, 0, 1);
  // 8. qf/kf/vf (token-major) = t3 @ cN_w^T + cN_b
  gemm64<0><<<dim3(4, 128), 256, 0, stream>>>(t, c1_w, c1_b, nullptr, qf, M_,
                                              256, 256, 0, 1);
  gemm64<0><<<dim3(4, 128), 256, 0, stream>>>(t, c2_w, c2_b, nullptr, kf, M_,
                                              256, 256, 0, 1);
  gemm64<0><<<dim3(4, 128), 256, 0, stream>>>(t, c3_w, c3_b, nullptr, vf, M_,
                                              256, 256, 0, 1);
  // 9. x2 = transpose(t3)
  transpose_kernel<<<8192, 256, 0, stream>>>(t, x2);
  // 10. channel scores
  chan_scores<<<dim3(4, 4, 8), 256, 0, stream>>>(qf, kf, amat);
  // 11. softmax rows
  softmax256<<<2048, 256, 0, stream>>>(amat);
  // 12. den_t = vf_t @ a_b^T (per-batch W)
  gemm64<0><<<dim3(4, 128), 256, 0, stream>>>(vf, amat, nullptr, nullptr, den,
                                              M_, 256, 256, 65536, 1024);
  // 13. final combine + depthwise conv
  final_kernel<<<8192, 256, 0, stream>>>(x2, den, dw_w, dw_b, out);
}

// Round 2
// 596.468 us; speedup vs baseline: 1.9815x; 1.9815x over previous
//
#include <hip/hip_runtime.h>
#include <math.h>

#define B_   8
#define C_   256
#define S_   1024
#define H_   8
#define DH_  32
#define M_   8192    // B_*S_
#define HID_ 1024
#define NELT 2097152 // B_*C_*S_

// ---------------- reduction helpers ----------------
__device__ __forceinline__ float waveReduceSum(float v) {
#pragma unroll
  for (int off = 32; off > 0; off >>= 1) v += __shfl_xor(v, off);
  return v;
}
__device__ __forceinline__ float waveReduceMax(float v) {
#pragma unroll
  for (int off = 32; off > 0; off >>= 1) v = fmaxf(v, __shfl_xor(v, off));
  return v;
}

// ---------------- LayerNorm (optionally reading x transposed) ----------------
template <int TRANSPOSED>
__global__ __launch_bounds__(256) void ln_kernel(const float* __restrict__ in,
                                                 const float* __restrict__ g,
                                                 const float* __restrict__ bta,
                                                 float* __restrict__ t,
                                                 float* __restrict__ tn) {
  __shared__ float s1s[4], s2s[4];
  int row = blockIdx.x;  // b*S + si
  int c = threadIdx.x;
  float v;
  if (TRANSPOSED) {
    int b = row >> 10, si = row & 1023;
    v = in[(((size_t)b * C_ + c) << 10) + si];
  } else {
    v = in[(size_t)row * C_ + c];
  }
  float s1 = waveReduceSum(v);
  float s2 = waveReduceSum(v * v);
  int wave = threadIdx.x >> 6;
  if ((threadIdx.x & 63) == 0) { s1s[wave] = s1; s2s[wave] = s2; }
  __syncthreads();
  s1 = s1s[0] + s1s[1] + s1s[2] + s1s[3];
  s2 = s2s[0] + s2s[1] + s2s[2] + s2s[3];
  float mu = s1 * (1.0f / 256.0f);
  float var = s2 * (1.0f / 256.0f) - mu * mu;
  float rs = rsqrtf(var + 1e-5f);
  size_t o = (size_t)row * C_ + c;
  if (TRANSPOSED) t[o] = v;
  tn[o] = (v - mu) * rs * g[c] + bta[c];
}

// ---------------- generic f32 GEMM: C = act(A @ W^T + bias) (+ res) ----------
__device__ __forceinline__ float gelu_exact(float v) {
  return 0.5f * v * (1.0f + erff(v * 0.70710678118654752f));
}

template <int ACT>  // 0 = none, 1 = exact gelu
__global__ __launch_bounds__(256) void gemm64(const float* __restrict__ A,
                                              const float* __restrict__ W,
                                              const float* __restrict__ bias,
                                              const float* __restrict__ res,
                                              float* __restrict__ Cout, int M,
                                              int Nn, int K, int w_bstride,
                                              int rows_per_batch) {
  __shared__ float As[32][68];
  __shared__ float Ws[32][68];
  int tid = threadIdx.x;
  int n0 = blockIdx.x * 64;
  int m0 = blockIdx.y * 64;
  const float* Wb = W;
  if (w_bstride) Wb += (size_t)(m0 / rows_per_batch) * w_bstride;
  float acc[4][4] = {};
  int tx = tid & 15, ty = tid >> 4;
  int lr = tid >> 3;         // 0..31
  int lk = (tid & 7) * 4;    // 0,4,...,28

  for (int k0 = 0; k0 < K; k0 += 32) {
    __syncthreads();
#pragma unroll
    for (int h = 0; h < 2; ++h) {
      int mm = lr + h * 32;
      float4 av = *(const float4*)&A[(size_t)(m0 + mm) * K + k0 + lk];
      As[lk + 0][mm] = av.x; As[lk + 1][mm] = av.y;
      As[lk + 2][mm] = av.z; As[lk + 3][mm] = av.w;
      float4 wv = *(const float4*)&Wb[(size_t)(n0 + mm) * K + k0 + lk];
      Ws[lk + 0][mm] = wv.x; Ws[lk + 1][mm] = wv.y;
      Ws[lk + 2][mm] = wv.z; Ws[lk + 3][mm] = wv.w;
    }
    __syncthreads();
#pragma unroll
    for (int kk = 0; kk < 32; ++kk) {
      float4 a4 = *(const float4*)&As[kk][ty * 4];
      float4 b4 = *(const float4*)&Ws[kk][tx * 4];
      float av[4] = {a4.x, a4.y, a4.z, a4.w};
      float bv[4] = {b4.x, b4.y, b4.z, b4.w};
#pragma unroll
      for (int i = 0; i < 4; ++i)
#pragma unroll
        for (int j = 0; j < 4; ++j) acc[i][j] += av[i] * bv[j];
    }
  }
#pragma unroll
  for (int i = 0; i < 4; ++i) {
    int mrow = m0 + ty * 4 + i;
#pragma unroll
    for (int j = 0; j < 4; ++j) {
      int ncol = n0 + tx * 4 + j;
      float v = acc[i][j];
      if (bias) v += bias[ncol];
      if (ACT == 1) v = gelu_exact(v);
      if (res) v += res[(size_t)mrow * Nn + ncol];
      Cout[(size_t)mrow * Nn + ncol] = v;
    }
  }
}

// ---------------- flash attention v2: thread-per-row, 4-way key split --------
// qkv: [B,S,768]. Each block: 256 threads = 256 q-rows of one (b,h), keys
// [ks*256, ks*256+256). Online softmax entirely thread-local; K/V staged in
// LDS, read as wave-uniform broadcasts (conflict-free).
__global__ __launch_bounds__(256, 4) void attn_part(
    const float* __restrict__ qkv, float* __restrict__ pacc,
    float* __restrict__ pm, float* __restrict__ pl) {
  __shared__ float Ks[128][32];
  __shared__ float Vs[128][32];
  int blk = blockIdx.x;            // [b(3)][h(3)][rc(2)][ks(2)]
  int ks = blk & 3;
  int rc = (blk >> 2) & 3;
  int h  = (blk >> 4) & 7;
  int b  = blk >> 7;
  int tid = threadIdx.x;
  int r = (rc << 8) + tid;
  const float* base = qkv + (size_t)b * S_ * 768 + h * 32;
  float q[32];
  {
    const float* qrow = base + (size_t)r * 768;
#pragma unroll
    for (int d4 = 0; d4 < 8; ++d4) {
      float4 v = *(const float4*)&qrow[d4 * 4];
      q[d4 * 4 + 0] = v.x; q[d4 * 4 + 1] = v.y;
      q[d4 * 4 + 2] = v.z; q[d4 * 4 + 3] = v.w;
    }
  }
  float m = -1e30f, l = 0.f;
  float acc[32] = {};
  const float scale = 0.17677669529663687f;  // 1/sqrt(32)
  int kbase = ks << 8;

  for (int tile = 0; tile < 2; ++tile) {
    __syncthreads();
    for (int i = tid; i < 1024; i += 256) {
      int row = i >> 3;
      int d4 = (i & 7) << 2;
      const float* kr =
          base + (size_t)(kbase + (tile << 7) + row) * 768 + 256 + d4;
      *(float4*)&Ks[row][d4] = *(const float4*)kr;
      *(float4*)&Vs[row][d4] = *(const float4*)(kr + 256);
    }
    __syncthreads();
    for (int kt = 0; kt < 8; ++kt) {  // 16 keys per subtile
      float st[16];
#pragma unroll
      for (int j = 0; j < 16; ++j) {
        const float* krow = Ks[kt * 16 + j];
        float s = 0.f;
#pragma unroll
        for (int d = 0; d < 32; ++d) s += q[d] * krow[d];
        st[j] = s * scale;
      }
      float tmax = st[0];
#pragma unroll
      for (int j = 1; j < 16; ++j) tmax = fmaxf(tmax, st[j]);
      float mnew = fmaxf(m, tmax);
      float corr = __expf(m - mnew);
      m = mnew;
      l *= corr;
#pragma unroll
      for (int d = 0; d < 32; ++d) acc[d] *= corr;
#pragma unroll
      for (int j = 0; j < 16; ++j) {
        float p = __expf(st[j] - mnew);
        l += p;
        const float* vrow = Vs[kt * 16 + j];
#pragma unroll
        for (int d = 0; d < 32; ++d) acc[d] += p * vrow[d];
      }
    }
  }
  int gr = (((b << 3) + h) << 10) + r;
  size_t pb = ((size_t)ks * 65536 + gr) * 32;
#pragma unroll
  for (int d4 = 0; d4 < 8; ++d4) {
    float4 v = {acc[d4 * 4], acc[d4 * 4 + 1], acc[d4 * 4 + 2],
                acc[d4 * 4 + 3]};
    *(float4*)&pacc[pb + d4 * 4] = v;
  }
  pm[ks * 65536 + gr] = m;
  pl[ks * 65536 + gr] = l;
}

// combine 4 split-K partials -> o [b,s,256]
__global__ __launch_bounds__(256) void attn_combine(
    const float* __restrict__ pacc, const float* __restrict__ pm,
    const float* __restrict__ pl, float* __restrict__ o) {
  int idx = blockIdx.x * 256 + threadIdx.x;  // 2M = 65536 rows * 32 dims
  int d = idx & 31;
  int gr = idx >> 5;
  float m0 = pm[gr], m1 = pm[65536 + gr];
  float m2 = pm[131072 + gr], m3 = pm[196608 + gr];
  float M = fmaxf(fmaxf(m0, m1), fmaxf(m2, m3));
  float w0 = __expf(m0 - M), w1 = __expf(m1 - M);
  float w2 = __expf(m2 - M), w3 = __expf(m3 - M);
  float L = w0 * pl[gr] + w1 * pl[65536 + gr] + w2 * pl[131072 + gr] +
            w3 * pl[196608 + gr];
  float v = w0 * pacc[(size_t)gr * 32 + d] +
            w1 * pacc[(size_t)(65536 + gr) * 32 + d] +
            w2 * pacc[(size_t)(131072 + gr) * 32 + d] +
            w3 * pacc[(size_t)(196608 + gr) * 32 + d];
  v /= L;
  int r = gr & 1023, h = (gr >> 10) & 7, b = gr >> 13;
  o[((size_t)((b << 10) + r)) * 256 + (h << 5) + d] = v;
}

// ---------------- transpose t3 [b,s,c] -> x2 [b,c,s] ----------------
__global__ __launch_bounds__(256) void transpose_kernel(const float* __restrict__ t,
                                                        float* __restrict__ x2) {
  int idx = blockIdx.x * 256 + threadIdx.x;  // [b][c][s] linear
  int si = idx & 1023;
  int c = (idx >> 10) & 255;
  int b = idx >> 18;
  x2[idx] = t[((size_t)b * S_ + si) * C_ + c];
}

// ---------------- channel scores: a_pre[b][i][j] = sum_s qf[s][i]*kf[s][j] ----
__global__ __launch_bounds__(256) void chan_scores(const float* __restrict__ qf,
                                                   const float* __restrict__ kf,
                                                   float* __restrict__ a_pre) {
  __shared__ float Qs[32][68];
  __shared__ float Ks[32][68];
  int b = blockIdx.z;
  int i0 = blockIdx.y * 64;
  int j0 = blockIdx.x * 64;
  const float* qb = qf + (size_t)b * S_ * C_;
  const float* kb_ = kf + (size_t)b * S_ * C_;
  int tid = threadIdx.x, tx = tid & 15, ty = tid >> 4;
  float acc[4][4] = {};
  for (int s0 = 0; s0 < S_; s0 += 32) {
    __syncthreads();
#pragma unroll
    for (int h = 0; h < 2; ++h) {
      int ss = (tid >> 4) + h * 16;
      int ii = (tid & 15) * 4;
      *(float4*)&Qs[ss][ii] = *(const float4*)&qb[(size_t)(s0 + ss) * C_ + i0 + ii];
      *(float4*)&Ks[ss][ii] = *(const float4*)&kb_[(size_t)(s0 + ss) * C_ + j0 + ii];
    }
    __syncthreads();
#pragma unroll
    for (int ss = 0; ss < 32; ++ss) {
      float4 a4 = *(const float4*)&Qs[ss][ty * 4];
      float4 b4 = *(const float4*)&Ks[ss][tx * 4];
      float av[4] = {a4.x, a4.y, a4.z, a4.w};
      float bv[4] = {b4.x, b4.y, b4.z, b4.w};
#pragma unroll
      for (int i = 0; i < 4; ++i)
#pragma unroll
        for (int j = 0; j < 4; ++j) acc[i][j] += av[i] * bv[j];
    }
  }
#pragma unroll
  for (int i = 0; i < 4; ++i)
#pragma unroll
    for (int j = 0; j < 4; ++j)
      a_pre[((size_t)b * C_ + i0 + ty * 4 + i) * C_ + j0 + tx * 4 + j] = acc[i][j];
}

// ---------------- row softmax over 256 ----------------
__global__ __launch_bounds__(256) void softmax256(float* __restrict__ a) {
  __shared__ float s1s[4];
  int row = blockIdx.x;
  int j = threadIdx.x;
  float v = a[(size_t)row * 256 + j];
  float mx = waveReduceMax(v);
  int wave = threadIdx.x >> 6;
  if ((threadIdx.x & 63) == 0) s1s[wave] = mx;
  __syncthreads();
  mx = fmaxf(fmaxf(s1s[0], s1s[1]), fmaxf(s1s[2], s1s[3]));
  __syncthreads();
  float e = __expf(v - mx);
  float ss = waveReduceSum(e);
  if ((threadIdx.x & 63) == 0) s1s[wave] = ss;
  __syncthreads();
  ss = s1s[0] + s1s[1] + s1s[2] + s1s[3];
  a[(size_t)row * 256 + j] = e / ss;
}

// ---------------- final: out = x2 + 0.1*den + 0.1*(dwconv3x3 + dw_b) --------
__global__ __launch_bounds__(256) void final_kernel(const float* __restrict__ x2,
                                                    const float* __restrict__ den_t,
                                                    const float* __restrict__ dww,
                                                    const float* __restrict__ dwb,
                                                    float* __restrict__ out) {
  int idx = blockIdx.x * 256 + threadIdx.x;  // out[b][c][y][x]
  int s = idx & 1023;
  int c = (idx >> 10) & 255;
  int b = idx >> 18;
  int y = s >> 5, x = s & 31;
  const float* plane = x2 + (size_t)(b * C_ + c) * S_;
  float lsum = 0.f;
#pragma unroll
  for (int dy = -1; dy <= 1; ++dy) {
    int yy = y + dy;
    if (yy < 0 || yy > 31) continue;
#pragma unroll
    for (int dx = -1; dx <= 1; ++dx) {
      int xx = x + dx;
      if (xx < 0 || xx > 31) continue;
      lsum += dww[c * 9 + (dy + 1) * 3 + (dx + 1)] * plane[yy * 32 + xx];
    }
  }
  lsum += dwb[c];
  float den = den_t[((size_t)b * S_ + s) * C_ + c];
  out[idx] = x2[idx] + 0.1f * den + 0.1f * lsum;
}

// =====================================================================
extern "C" void kernel_launch(void* const* d_in, const int* in_sizes, int n_in,
                              void* d_out, int out_size, void* d_ws,
                              size_t ws_size, hipStream_t stream) {
  const float* x     = (const float*)d_in[0];
  const float* ln1_g = (const float*)d_in[1];
  const float* ln1_b = (const float*)d_in[2];
  const float* wqkv  = (const float*)d_in[3];
  const float* bqkv  = (const float*)d_in[4];
  const float* wo    = (const float*)d_in[5];
  const float* bo    = (const float*)d_in[6];
  const float* ln2_g = (const float*)d_in[7];
  const float* ln2_b = (const float*)d_in[8];
  const float* w1    = (const float*)d_in[9];
  const float* b1    = (const float*)d_in[10];
  const float* w2    = (const float*)d_in[11];
  const float* b2    = (const float*)d_in[12];
  const float* c1_w  = (const float*)d_in[13];
  const float* c1_b  = (const float*)d_in[14];
  const float* c2_w  = (const float*)d_in[15];
  const float* c2_b  = (const float*)d_in[16];
  const float* c3_w  = (const float*)d_in[17];
  const float* c3_b  = (const float*)d_in[18];
  const float* dw_w  = (const float*)d_in[19];
  const float* dw_b  = (const float*)d_in[20];
  float* out = (float*)d_out;

  // workspace layout (floats); needs 10*NELT*4 = 84 MB
  float* ws = (float*)d_ws;
  const size_t N = NELT;
  float* t   = ws;            // t -> t2 -> t3 (in place)
  float* tn  = ws + N;        // tn -> (attn pm/pl scratch) -> tn2
  float* qkv = ws + 2 * N;    // 3N; later qf@2N, kf@3N, vf@4N
  float* obf = ws + 5 * N;    // o; later x2
  float* hdn = ws + 6 * N;    // 4N; attn pacc lives here first, then hdn/a/den
  float* qf  = ws + 2 * N;
  float* kf  = ws + 3 * N;
  float* vf  = ws + 4 * N;
  float* x2  = ws + 5 * N;
  float* amat = ws + 6 * N;   // [8,256,256]
  float* den  = ws + 7 * N;   // den_t [b,s,c]
  float* pacc = ws + 6 * N;   // [4,65536,32] = 4N floats (attn scratch)
  float* pm   = ws + N;       // [4,65536]
  float* pl   = ws + N + 262144;

  // 1. transpose + LN1
  ln_kernel<1><<<M_, 256, 0, stream>>>(x, ln1_g, ln1_b, t, tn);
  // 2. qkv = tn @ wqkv^T + bqkv
  gemm64<0><<<dim3(12, 128), 256, 0, stream>>>(tn, wqkv, bqkv, nullptr, qkv,
                                               M_, 768, 256, 0, 1);
  // 3. attention (split-K flash, thread-per-row) + combine
  attn_part<<<1024, 256, 0, stream>>>(qkv, pacc, pm, pl);
  attn_combine<<<8192, 256, 0, stream>>>(pacc, pm, pl, obf);
  // 4. t2 = t + o @ wo^T + bo (in-place on t)
  gemm64<0><<<dim3(4, 128), 256, 0, stream>>>(obf, wo, bo, t, t, M_, 256, 256,
                                              0, 1);
  // 5. tn2 = LN2(t2)
  ln_kernel<0><<<M_, 256, 0, stream>>>(t, ln2_g, ln2_b, nullptr, tn);
  // 6. hdn = gelu(tn2 @ w1^T + b1)
  gemm64<1><<<dim3(16, 128), 256, 0, stream>>>(tn, w1, b1, nullptr, hdn, M_,
                                               HID_, 256, 0, 1);
  // 7. t3 = t2 + hdn @ w2^T + b2 (in-place on t)
  gemm64<0><<<dim3(4, 128), 256, 0, stream>>>(hdn, w2, b2, t, t, M_, 256,
                                              HID_, 0, 1);
  // 8. qf/kf/vf (token-major) = t3 @ cN_w^T + cN_b
  gemm64<0><<<dim3(4, 128), 256, 0, stream>>>(t, c1_w, c1_b, nullptr, qf, M_,
                                              256, 256, 0, 1);
  gemm64<0><<<dim3(4, 128), 256, 0, stream>>>(t, c2_w, c2_b, nullptr, kf, M_,
                                              256, 256, 0, 1);
  gemm64<0><<<dim3(4, 128), 256, 0, stream>>>(t, c3_w, c3_b, nullptr, vf, M_,
                                              256, 256, 0, 1);
  // 9. x2 = transpose(t3)
  transpose_kernel<<<8192, 256, 0, stream>>>(t, x2);
  // 10. channel scores
  chan_scores<<<dim3(4, 4, 8), 256, 0, stream>>>(qf, kf, amat);
  // 11. softmax rows
  softmax256<<<2048, 256, 0, stream>>>(amat);
  // 12. den_t = vf_t @ a_b^T (per-batch W)
  gemm64<0><<<dim3(4, 128), 256, 0, stream>>>(vf, amat, nullptr, nullptr, den,
                                              M_, 256, 256, 65536, 1024);
  // 13. final combine + depthwise conv
  final_kernel<<<8192, 256, 0, stream>>>(x2, den, dw_w, dw_b, out);
}

// Round 3
// 420.925 us; speedup vs baseline: 2.8078x; 1.4170x over previous
//
#include <hip/hip_runtime.h>
#include <math.h>

#define B_   8
#define C_   256
#define S_   1024
#define M_   8192    // B_*S_
#define HID_ 1024
#define NELT 2097152 // B_*C_*S_

typedef __attribute__((ext_vector_type(4))) float f32x4;
typedef __attribute__((ext_vector_type(8))) short bf16x8;

__device__ __forceinline__ ushort f2bf(float f) {
  union { float f; unsigned u; } c; c.f = f;
  unsigned u = c.u;
  return (ushort)((u + 0x7fff + ((u >> 16) & 1)) >> 16);
}

// ---------------- reduction helpers ----------------
__device__ __forceinline__ float waveReduceSum(float v) {
#pragma unroll
  for (int off = 32; off > 0; off >>= 1) v += __shfl_xor(v, off);
  return v;
}

// ---------------- LayerNorm: writes f32 copy (opt) + bf16 normalized -------
template <int TRANSPOSED>
__global__ __launch_bounds__(256) void ln_kernel(const float* __restrict__ in,
                                                 const float* __restrict__ g,
                                                 const float* __restrict__ bta,
                                                 float* __restrict__ t,
                                                 ushort* __restrict__ tn) {
  __shared__ float s1s[4], s2s[4];
  int row = blockIdx.x;  // b*S + si
  int c = threadIdx.x;
  float v;
  if (TRANSPOSED) {
    int b = row >> 10, si = row & 1023;
    v = in[(((size_t)b * C_ + c) << 10) + si];
  } else {
    v = in[(size_t)row * C_ + c];
  }
  float s1 = waveReduceSum(v);
  float s2 = waveReduceSum(v * v);
  int wave = threadIdx.x >> 6;
  if ((threadIdx.x & 63) == 0) { s1s[wave] = s1; s2s[wave] = s2; }
  __syncthreads();
  s1 = s1s[0] + s1s[1] + s1s[2] + s1s[3];
  s2 = s2s[0] + s2s[1] + s2s[2] + s2s[3];
  float mu = s1 * (1.0f / 256.0f);
  float var = s2 * (1.0f / 256.0f) - mu * mu;
  float rs = rsqrtf(var + 1e-5f);
  size_t o = (size_t)row * C_ + c;
  if (TRANSPOSED) t[o] = v;
  tn[o] = f2bf((v - mu) * rs * g[c] + bta[c]);
}

// ---------------- weight convert f32 -> bf16 (all 7 weights) ----------------
__global__ __launch_bounds__(256) void cvt7(
    const float* __restrict__ s0, const float* __restrict__ s1,
    const float* __restrict__ s2, const float* __restrict__ s3,
    const float* __restrict__ s4, const float* __restrict__ s5,
    const float* __restrict__ s6, ushort* __restrict__ dst) {
  int i = blockIdx.x * 256 + threadIdx.x;
  const float* s; int off;
  if (i < 196608)      { s = s0; off = 0; }
  else if (i < 262144) { s = s1; off = 196608; }
  else if (i < 524288) { s = s2; off = 262144; }
  else if (i < 786432) { s = s3; off = 524288; }
  else if (i < 851968) { s = s4; off = 786432; }
  else if (i < 917504) { s = s5; off = 851968; }
  else                 { s = s6; off = 917504; }
  dst[i] = f2bf(s[i - off]);
}

// ---------------- bf16 MFMA GEMM: C = act(A @ W^T + bias) (+res) -----------
// A: [M,K] bf16 row-major (opt per-batch: row = m % a_rpb, base += (m/a_rpb)*a_bstride)
// W: [N,K] bf16 row-major (opt per-batch by m: base += (m0/w_rpb)*w_bstride)
// 128x128 tile, 4 waves, BK=32, 16x16x32 MFMA, XOR chunk swizzle in LDS.
__device__ __forceinline__ int swzr(int r) { return (r ^ (r >> 2)) & 3; }
__device__ __forceinline__ float gelu_exact(float v) {
  return 0.5f * v * (1.0f + erff(v * 0.70710678118654752f));
}

template <int ACT, int OBF, int DUAL, int BROW>
__global__ __launch_bounds__(256) void gemm_bf16(
    const ushort* __restrict__ A, const ushort* __restrict__ W,
    const float* __restrict__ bias, const float* __restrict__ res,
    float* __restrict__ Cf, ushort* __restrict__ Cb, int M, int Nn, int K,
    int a_rpb, long long a_bstride, int w_rpb, long long w_bstride) {
  __shared__ ushort As[4096];  // [128][32]
  __shared__ ushort Bs[4096];
  int tid = threadIdx.x;
  int lane = tid & 63, wave = tid >> 6;
  int m0 = blockIdx.y * 128, n0 = blockIdx.x * 128;
  const ushort* Ab;
  if (a_rpb)
    Ab = A + (size_t)(m0 / a_rpb) * a_bstride + (size_t)(m0 % a_rpb) * K;
  else
    Ab = A + (size_t)m0 * K;
  const ushort* Wb = W + (size_t)n0 * K;
  if (w_rpb) Wb += (size_t)(m0 / w_rpb) * w_bstride;
  int srow = tid >> 2;   // 0..63
  int sch = tid & 3;     // k-chunk 0..3
  int fr = lane & 15, fh = lane >> 4;
  int wr = (wave >> 1) * 64, wc = (wave & 1) * 64;
  f32x4 acc[4][4];
#pragma unroll
  for (int i = 0; i < 4; ++i)
#pragma unroll
    for (int j = 0; j < 4; ++j) acc[i][j] = (f32x4){0.f, 0.f, 0.f, 0.f};

  int sw0 = (sch ^ swzr(srow)) * 8;
  int sw1 = (sch ^ swzr(srow + 64)) * 8;
  for (int k0 = 0; k0 < K; k0 += 32) {
    uint4 a0 = *(const uint4*)&Ab[(size_t)srow * K + k0 + sch * 8];
    uint4 a1 = *(const uint4*)&Ab[(size_t)(srow + 64) * K + k0 + sch * 8];
    uint4 b0 = *(const uint4*)&Wb[(size_t)srow * K + k0 + sch * 8];
    uint4 b1 = *(const uint4*)&Wb[(size_t)(srow + 64) * K + k0 + sch * 8];
    __syncthreads();
    *(uint4*)&As[srow * 32 + sw0] = a0;
    *(uint4*)&As[(srow + 64) * 32 + sw1] = a1;
    *(uint4*)&Bs[srow * 32 + sw0] = b0;
    *(uint4*)&Bs[(srow + 64) * 32 + sw1] = b1;
    __syncthreads();
    bf16x8 af[4], bfv[4];
#pragma unroll
    for (int mi = 0; mi < 4; ++mi) {
      int r = wr + mi * 16 + fr;
      af[mi] = *(const bf16x8*)&As[r * 32 + ((fh ^ swzr(r)) * 8)];
    }
#pragma unroll
    for (int ni = 0; ni < 4; ++ni) {
      int r = wc + ni * 16 + fr;
      bfv[ni] = *(const bf16x8*)&Bs[r * 32 + ((fh ^ swzr(r)) * 8)];
    }
#pragma unroll
    for (int mi = 0; mi < 4; ++mi)
#pragma unroll
      for (int ni = 0; ni < 4; ++ni)
        acc[mi][ni] = __builtin_amdgcn_mfma_f32_16x16x32_bf16(
            af[mi], bfv[ni], acc[mi][ni], 0, 0, 0);
  }
  // epilogue: C/D layout col=lane&15, row=(lane>>4)*4+r
#pragma unroll
  for (int mi = 0; mi < 4; ++mi) {
    int rowb = m0 + wr + mi * 16 + fh * 4;
#pragma unroll
    for (int ni = 0; ni < 4; ++ni) {
      int col = n0 + wc + ni * 16 + fr;
      float bv = 0.f;
      if (bias && !BROW) bv = bias[col];
#pragma unroll
      for (int r = 0; r < 4; ++r) {
        int row = rowb + r;
        float v = acc[mi][ni][r];
        if (bias && BROW) bv = bias[row & 255];
        v += bv;
        if (ACT == 1) v = gelu_exact(v);
        if (res) v += res[(size_t)row * Nn + col];
        size_t o = (size_t)row * Nn + col;
        if (OBF) {
          Cb[o] = f2bf(v);
        } else {
          Cf[o] = v;
          if (DUAL) Cb[o] = f2bf(v);
        }
      }
    }
  }
}

// ---------------- flash attention: thread-per-row, 4-way key split ----------
__global__ __launch_bounds__(256, 4) void attn_part(
    const float* __restrict__ qkv, float* __restrict__ pacc,
    float* __restrict__ pm, float* __restrict__ pl) {
  __shared__ float Ks[128][32];
  __shared__ float Vs[128][32];
  int blk = blockIdx.x;  // [b(3)][h(3)][rc(2)][ks(2)]
  int ks = blk & 3;
  int rc = (blk >> 2) & 3;
  int h = (blk >> 4) & 7;
  int b = blk >> 7;
  int tid = threadIdx.x;
  int r = (rc << 8) + tid;
  const float* base = qkv + (size_t)b * S_ * 768 + h * 32;
  float q[32];
  {
    const float* qrow = base + (size_t)r * 768;
#pragma unroll
    for (int d4 = 0; d4 < 8; ++d4) {
      float4 v = *(const float4*)&qrow[d4 * 4];
      q[d4 * 4 + 0] = v.x; q[d4 * 4 + 1] = v.y;
      q[d4 * 4 + 2] = v.z; q[d4 * 4 + 3] = v.w;
    }
  }
  float m = -1e30f, l = 0.f;
  float acc[32] = {};
  const float scale = 0.17677669529663687f;
  int kbase = ks << 8;

  for (int tile = 0; tile < 2; ++tile) {
    __syncthreads();
    for (int i = tid; i < 1024; i += 256) {
      int row = i >> 3;
      int d4 = (i & 7) << 2;
      const float* kr =
          base + (size_t)(kbase + (tile << 7) + row) * 768 + 256 + d4;
      *(float4*)&Ks[row][d4] = *(const float4*)kr;
      *(float4*)&Vs[row][d4] = *(const float4*)(kr + 256);
    }
    __syncthreads();
    for (int kt = 0; kt < 8; ++kt) {
      float st[16];
#pragma unroll
      for (int j = 0; j < 16; ++j) {
        const float* krow = Ks[kt * 16 + j];
        float s = 0.f;
#pragma unroll
        for (int d = 0; d < 32; ++d) s += q[d] * krow[d];
        st[j] = s * scale;
      }
      float tmax = st[0];
#pragma unroll
      for (int j = 1; j < 16; ++j) tmax = fmaxf(tmax, st[j]);
      float mnew = fmaxf(m, tmax);
      float corr = __expf(m - mnew);
      m = mnew;
      l *= corr;
#pragma unroll
      for (int d = 0; d < 32; ++d) acc[d] *= corr;
#pragma unroll
      for (int j = 0; j < 16; ++j) {
        float p = __expf(st[j] - mnew);
        l += p;
        const float* vrow = Vs[kt * 16 + j];
#pragma unroll
        for (int d = 0; d < 32; ++d) acc[d] += p * vrow[d];
      }
    }
  }
  int gr = (((b << 3) + h) << 10) + r;
  size_t pb = ((size_t)ks * 65536 + gr) * 32;
#pragma unroll
  for (int d4 = 0; d4 < 8; ++d4) {
    float4 v = {acc[d4 * 4], acc[d4 * 4 + 1], acc[d4 * 4 + 2],
                acc[d4 * 4 + 3]};
    *(float4*)&pacc[pb + d4 * 4] = v;
  }
  pm[ks * 65536 + gr] = m;
  pl[ks * 65536 + gr] = l;
}

// combine 4 split-K partials -> o_bf [b,s,256] (bf16)
__global__ __launch_bounds__(256) void attn_combine(
    const float* __restrict__ pacc, const float* __restrict__ pm,
    const float* __restrict__ pl, ushort* __restrict__ o) {
  int idx = blockIdx.x * 256 + threadIdx.x;
  int d = idx & 31;
  int gr = idx >> 5;
  float m0 = pm[gr], m1 = pm[65536 + gr];
  float m2 = pm[131072 + gr], m3 = pm[196608 + gr];
  float M = fmaxf(fmaxf(m0, m1), fmaxf(m2, m3));
  float w0 = __expf(m0 - M), w1 = __expf(m1 - M);
  float w2 = __expf(m2 - M), w3 = __expf(m3 - M);
  float L = w0 * pl[gr] + w1 * pl[65536 + gr] + w2 * pl[131072 + gr] +
            w3 * pl[196608 + gr];
  float v = w0 * pacc[(size_t)gr * 32 + d] +
            w1 * pacc[(size_t)(65536 + gr) * 32 + d] +
            w2 * pacc[(size_t)(131072 + gr) * 32 + d] +
            w3 * pacc[(size_t)(196608 + gr) * 32 + d];
  v /= L;
  int r = gr & 1023, h = (gr >> 10) & 7, b = gr >> 13;
  o[((size_t)((b << 10) + r)) * 256 + (h << 5) + d] = f2bf(v);
}

// ---------------- transpose t3 [b,s,c] -> x2 [b,c,s] ----------------
__global__ __launch_bounds__(256) void transpose_kernel(
    const float* __restrict__ t, float* __restrict__ x2) {
  int idx = blockIdx.x * 256 + threadIdx.x;
  int si = idx & 1023;
  int c = (idx >> 10) & 255;
  int b = idx >> 18;
  x2[idx] = t[((size_t)b * S_ + si) * C_ + c];
}

// ---------------- row softmax over 256, f32 in -> bf16 out ----------------
__global__ __launch_bounds__(256) void softmax256(const float* __restrict__ a,
                                                  ushort* __restrict__ ab) {
  __shared__ float s1s[4];
  int row = blockIdx.x;
  int j = threadIdx.x;
  float v = a[(size_t)row * 256 + j];
  float mx = v;
#pragma unroll
  for (int off = 32; off > 0; off >>= 1) mx = fmaxf(mx, __shfl_xor(mx, off));
  int wave = threadIdx.x >> 6;
  if ((threadIdx.x & 63) == 0) s1s[wave] = mx;
  __syncthreads();
  mx = fmaxf(fmaxf(s1s[0], s1s[1]), fmaxf(s1s[2], s1s[3]));
  __syncthreads();
  float e = __expf(v - mx);
  float ss = waveReduceSum(e);
  if ((threadIdx.x & 63) == 0) s1s[wave] = ss;
  __syncthreads();
  ss = s1s[0] + s1s[1] + s1s[2] + s1s[3];
  ab[(size_t)row * 256 + j] = f2bf(e / ss);
}

// ---------------- final: out = x2 + 0.1*den_c + 0.1*(dw3x3 + dw_b) ---------
__global__ __launch_bounds__(256) void final_kernel(
    const float* __restrict__ x2, const float* __restrict__ den_c,
    const float* __restrict__ dww, const float* __restrict__ dwb,
    float* __restrict__ out) {
  int idx = blockIdx.x * 256 + threadIdx.x;  // [b][c][y][x]
  int s = idx & 1023;
  int c = (idx >> 10) & 255;
  int b = idx >> 18;
  int y = s >> 5, x = s & 31;
  const float* plane = x2 + (size_t)(b * C_ + c) * S_;
  float lsum = 0.f;
#pragma unroll
  for (int dy = -1; dy <= 1; ++dy) {
    int yy = y + dy;
    if (yy < 0 || yy > 31) continue;
#pragma unroll
    for (int dx = -1; dx <= 1; ++dx) {
      int xx = x + dx;
      if (xx < 0 || xx > 31) continue;
      lsum += dww[c * 9 + (dy + 1) * 3 + (dx + 1)] * plane[yy * 32 + xx];
    }
  }
  lsum += dwb[c];
  out[idx] = x2[idx] + 0.1f * den_c[idx] + 0.1f * lsum;
}

// =====================================================================
extern "C" void kernel_launch(void* const* d_in, const int* in_sizes, int n_in,
                              void* d_out, int out_size, void* d_ws,
                              size_t ws_size, hipStream_t stream) {
  const float* x     = (const float*)d_in[0];
  const float* ln1_g = (const float*)d_in[1];
  const float* ln1_b = (const float*)d_in[2];
  const float* wqkv  = (const float*)d_in[3];
  const float* bqkv  = (const float*)d_in[4];
  const float* wo    = (const float*)d_in[5];
  const float* bo    = (const float*)d_in[6];
  const float* ln2_g = (const float*)d_in[7];
  const float* ln2_b = (const float*)d_in[8];
  const float* w1    = (const float*)d_in[9];
  const float* b1    = (const float*)d_in[10];
  const float* b2w   = (const float*)d_in[11];  // w2
  const float* b2    = (const float*)d_in[12];
  const float* c1_w  = (const float*)d_in[13];
  const float* c1_b  = (const float*)d_in[14];
  const float* c2_w  = (const float*)d_in[15];
  const float* c2_b  = (const float*)d_in[16];
  const float* c3_w  = (const float*)d_in[17];
  const float* c3_b  = (const float*)d_in[18];
  const float* dw_w  = (const float*)d_in[19];
  const float* dw_b  = (const float*)d_in[20];
  float* out = (float*)d_out;

  // workspace layout, float units, N = 2M. Total 9.5N = 76 MB.
  float* ws = (float*)d_ws;
  const size_t N = NELT;
  float* t     = ws;                    // [0,N) f32, lives until transpose
  float* qkv   = ws + N;                // [N,4N) f32, dead after combine
  float* x2    = ws + N;                // reuse [N,2N) after qkv dead
  float* den_c = ws + 2 * N;            // [2N,3N)
  ushort* hdn_bf = (ushort*)(ws + 3 * N);   // [3N,4N)
  float* pacc  = ws + 4 * N;            // [4N,8N) f32, dead after combine
  ushort* t_bf = (ushort*)(ws + 4 * N);     // reuse
  ushort* qf_c = (ushort*)(ws + 4 * N + N / 2);
  ushort* kf_c = (ushort*)(ws + 5 * N);
  ushort* vf   = (ushort*)(ws + 5 * N + N / 2);
  float* amat  = ws + 6 * N;            // [6N,6.25N)
  ushort* amat_bf = (ushort*)(ws + 6 * N + N / 4);
  ushort* tn_bf = (ushort*)(ws + 8 * N);    // [8N,8.5N)
  ushort* o_bf  = (ushort*)(ws + 8 * N + N / 2);
  float* pm = ws + 9 * N;               // 262144
  float* pl = ws + 9 * N + 262144;
  ushort* wbf = (ushort*)(ws + 9 * N + N / 4);  // 983040 bf16
  ushort* wqkv_bf = wbf;
  ushort* wo_bf   = wbf + 196608;
  ushort* w1_bf   = wbf + 262144;
  ushort* w2_bf   = wbf + 524288;
  ushort* c1_bf   = wbf + 786432;
  ushort* c2_bf   = wbf + 851968;
  ushort* c3_bf   = wbf + 917504;

  const long long PB = 262144;  // per-batch stride (1024*256) in elements

  // 0. weights -> bf16
  cvt7<<<3840, 256, 0, stream>>>(wqkv, wo, w1, b2w, c1_w, c2_w, c3_w, wbf);
  // 1. transpose + LN1 (writes t f32, tn bf16)
  ln_kernel<1><<<M_, 256, 0, stream>>>(x, ln1_g, ln1_b, t, tn_bf);
  // 2. qkv = tn @ wqkv^T + bqkv  (f32 out for attention)
  gemm_bf16<0, 0, 0, 0><<<dim3(6, 64), 256, 0, stream>>>(
      tn_bf, wqkv_bf, bqkv, nullptr, qkv, nullptr, M_, 768, 256, 0, 0, 0, 0);
  // 3. attention
  attn_part<<<1024, 256, 0, stream>>>(qkv, pacc, pm, pl);
  attn_combine<<<8192, 256, 0, stream>>>(pacc, pm, pl, o_bf);
  // 4. t = t + o @ wo^T + bo
  gemm_bf16<0, 0, 0, 0><<<dim3(2, 64), 256, 0, stream>>>(
      o_bf, wo_bf, bo, t, t, nullptr, M_, 256, 256, 0, 0, 0, 0);
  // 5. tn = LN2(t)
  ln_kernel<0><<<M_, 256, 0, stream>>>(t, ln2_g, ln2_b, nullptr, tn_bf);
  // 6. hdn = gelu(tn @ w1^T + b1) -> bf16
  gemm_bf16<1, 1, 0, 0><<<dim3(8, 64), 256, 0, stream>>>(
      tn_bf, w1_bf, b1, nullptr, nullptr, hdn_bf, M_, HID_, 256, 0, 0, 0, 0);
  // 7. t = t + hdn @ w2^T + b2 (dual write f32 + bf16)
  gemm_bf16<0, 0, 1, 0><<<dim3(2, 64), 256, 0, stream>>>(
      hdn_bf, w2_bf, b2, t, t, t_bf, M_, 256, HID_, 0, 0, 0, 0);
  // 8a. qf_c[b,c,s] = c1_w @ t3_b^T + c1_b (A=weight broadcast, W=t_bf/batch)
  gemm_bf16<0, 1, 0, 1><<<dim3(8, 16), 256, 0, stream>>>(
      c1_bf, t_bf, c1_b, nullptr, nullptr, qf_c, 2048, 1024, 256, 256, 0, 256,
      PB);
  gemm_bf16<0, 1, 0, 1><<<dim3(8, 16), 256, 0, stream>>>(
      c2_bf, t_bf, c2_b, nullptr, nullptr, kf_c, 2048, 1024, 256, 256, 0, 256,
      PB);
  // 8b. vf[b,s,c] = t3 @ c3_w^T + c3_b (token-major)
  gemm_bf16<0, 1, 0, 0><<<dim3(2, 64), 256, 0, stream>>>(
      t_bf, c3_bf, c3_b, nullptr, nullptr, vf, M_, 256, 256, 0, 0, 0, 0);
  // 9. x2 = transpose(t3)
  transpose_kernel<<<8192, 256, 0, stream>>>(t, x2);
  // 10. amat[b,i,j] = qf_c[b,i,:] . kf_c[b,j,:]
  gemm_bf16<0, 0, 0, 0><<<dim3(2, 16), 256, 0, stream>>>(
      qf_c, kf_c, nullptr, nullptr, amat, nullptr, 2048, 256, 1024, 256, PB,
      256, PB);
  // 11. softmax rows -> bf16
  softmax256<<<2048, 256, 0, stream>>>(amat, amat_bf);
  // 12. den_c[b,c,s] = a_b @ vf_b^T
  gemm_bf16<0, 0, 0, 0><<<dim3(8, 16), 256, 0, stream>>>(
      amat_bf, vf, nullptr, nullptr, den_c, nullptr, 2048, 1024, 256, 0, 0,
      256, PB);
  // 13. final combine + depthwise conv
  final_kernel<<<8192, 256, 0, stream>>>(x2, den_c, dw_w, dw_b, out);
}

// Round 4
// 291.714 us; speedup vs baseline: 4.0515x; 1.4429x over previous
//
#include <hip/hip_runtime.h>
#include <hip/hip_bf16.h>
#include <math.h>

#define B_   8
#define C_   256
#define S_   1024
#define M_   8192    // B_*S_
#define HID_ 1024
#define NELT 2097152 // B_*C_*S_

typedef __attribute__((ext_vector_type(4))) float f32x4;
typedef __attribute__((ext_vector_type(8))) short bf16x8;

__device__ __forceinline__ ushort f2bf(float f) {
  union { float f; unsigned u; } c; c.f = f;
  unsigned u = c.u;
  return (ushort)((u + 0x7fff + ((u >> 16) & 1)) >> 16);
}
__device__ __forceinline__ ushort f2bf_fast(float f) {
  __hip_bfloat16 h = __float2bfloat16(f);
  return *reinterpret_cast<ushort*>(&h);
}

// ---------------- reduction helpers ----------------
__device__ __forceinline__ float waveReduceSum(float v) {
#pragma unroll
  for (int off = 32; off > 0; off >>= 1) v += __shfl_xor(v, off);
  return v;
}

// ---------------- LayerNorm: writes f32 copy (opt) + bf16 normalized -------
template <int TRANSPOSED>
__global__ __launch_bounds__(256) void ln_kernel(const float* __restrict__ in,
                                                 const float* __restrict__ g,
                                                 const float* __restrict__ bta,
                                                 float* __restrict__ t,
                                                 ushort* __restrict__ tn) {
  __shared__ float s1s[4], s2s[4];
  int row = blockIdx.x;  // b*S + si
  int c = threadIdx.x;
  float v;
  if (TRANSPOSED) {
    int b = row >> 10, si = row & 1023;
    v = in[(((size_t)b * C_ + c) << 10) + si];
  } else {
    v = in[(size_t)row * C_ + c];
  }
  float s1 = waveReduceSum(v);
  float s2 = waveReduceSum(v * v);
  int wave = threadIdx.x >> 6;
  if ((threadIdx.x & 63) == 0) { s1s[wave] = s1; s2s[wave] = s2; }
  __syncthreads();
  s1 = s1s[0] + s1s[1] + s1s[2] + s1s[3];
  s2 = s2s[0] + s2s[1] + s2s[2] + s2s[3];
  float mu = s1 * (1.0f / 256.0f);
  float var = s2 * (1.0f / 256.0f) - mu * mu;
  float rs = rsqrtf(var + 1e-5f);
  size_t o = (size_t)row * C_ + c;
  if (TRANSPOSED) t[o] = v;
  tn[o] = f2bf((v - mu) * rs * g[c] + bta[c]);
}

// ---------------- weight convert f32 -> bf16 (all 7 weights) ----------------
__global__ __launch_bounds__(256) void cvt7(
    const float* __restrict__ s0, const float* __restrict__ s1,
    const float* __restrict__ s2, const float* __restrict__ s3,
    const float* __restrict__ s4, const float* __restrict__ s5,
    const float* __restrict__ s6, ushort* __restrict__ dst) {
  int i = blockIdx.x * 256 + threadIdx.x;
  const float* s; int off;
  if (i < 196608)      { s = s0; off = 0; }
  else if (i < 262144) { s = s1; off = 196608; }
  else if (i < 524288) { s = s2; off = 262144; }
  else if (i < 786432) { s = s3; off = 524288; }
  else if (i < 851968) { s = s4; off = 786432; }
  else if (i < 917504) { s = s5; off = 851968; }
  else                 { s = s6; off = 917504; }
  dst[i] = f2bf(s[i - off]);
}

// ---------------- bf16 MFMA GEMM: C = act(A @ W^T + bias) (+res) -----------
// EPI: 0 = f32 out, 1 = bf16 out, 3 = qkv (bf16 q/k + transposed v_t),
//      4 = bf16 out + f32 transposed x2
__device__ __forceinline__ int swzr(int r) { return (r ^ (r >> 2)) & 3; }
__device__ __forceinline__ float gelu_exact(float v) {
  return 0.5f * v * (1.0f + erff(v * 0.70710678118654752f));
}

template <int ACT, int EPI, int BROW>
__global__ __launch_bounds__(256) void gemm_bf16(
    const ushort* __restrict__ A, const ushort* __restrict__ W,
    const float* __restrict__ bias, const float* __restrict__ res,
    float* __restrict__ Cf, ushort* __restrict__ Cb, void* __restrict__ Cx,
    int M, int Nn, int K,
    int a_rpb, long long a_bstride, int w_rpb, long long w_bstride) {
  __shared__ ushort As[4096];  // [128][32]
  __shared__ ushort Bs[4096];
  int tid = threadIdx.x;
  int lane = tid & 63, wave = tid >> 6;
  int m0 = blockIdx.y * 128, n0 = blockIdx.x * 128;
  const ushort* Ab;
  if (a_rpb)
    Ab = A + (size_t)(m0 / a_rpb) * a_bstride + (size_t)(m0 % a_rpb) * K;
  else
    Ab = A + (size_t)m0 * K;
  const ushort* Wb = W + (size_t)n0 * K;
  if (w_rpb) Wb += (size_t)(m0 / w_rpb) * w_bstride;
  int srow = tid >> 2;   // 0..63
  int sch = tid & 3;     // k-chunk 0..3
  int fr = lane & 15, fh = lane >> 4;
  int wr = (wave >> 1) * 64, wc = (wave & 1) * 64;
  f32x4 acc[4][4];
#pragma unroll
  for (int i = 0; i < 4; ++i)
#pragma unroll
    for (int j = 0; j < 4; ++j) acc[i][j] = (f32x4){0.f, 0.f, 0.f, 0.f};

  int sw0 = (sch ^ swzr(srow)) * 8;
  int sw1 = (sch ^ swzr(srow + 64)) * 8;
  for (int k0 = 0; k0 < K; k0 += 32) {
    uint4 a0 = *(const uint4*)&Ab[(size_t)srow * K + k0 + sch * 8];
    uint4 a1 = *(const uint4*)&Ab[(size_t)(srow + 64) * K + k0 + sch * 8];
    uint4 b0 = *(const uint4*)&Wb[(size_t)srow * K + k0 + sch * 8];
    uint4 b1 = *(const uint4*)&Wb[(size_t)(srow + 64) * K + k0 + sch * 8];
    __syncthreads();
    *(uint4*)&As[srow * 32 + sw0] = a0;
    *(uint4*)&As[(srow + 64) * 32 + sw1] = a1;
    *(uint4*)&Bs[srow * 32 + sw0] = b0;
    *(uint4*)&Bs[(srow + 64) * 32 + sw1] = b1;
    __syncthreads();
    bf16x8 af[4], bfv[4];
#pragma unroll
    for (int mi = 0; mi < 4; ++mi) {
      int r = wr + mi * 16 + fr;
      af[mi] = *(const bf16x8*)&As[r * 32 + ((fh ^ swzr(r)) * 8)];
    }
#pragma unroll
    for (int ni = 0; ni < 4; ++ni) {
      int r = wc + ni * 16 + fr;
      bfv[ni] = *(const bf16x8*)&Bs[r * 32 + ((fh ^ swzr(r)) * 8)];
    }
#pragma unroll
    for (int mi = 0; mi < 4; ++mi)
#pragma unroll
      for (int ni = 0; ni < 4; ++ni)
        acc[mi][ni] = __builtin_amdgcn_mfma_f32_16x16x32_bf16(
            af[mi], bfv[ni], acc[mi][ni], 0, 0, 0);
  }
  // epilogue: C/D layout col=lane&15, row=(lane>>4)*4+r
#pragma unroll
  for (int mi = 0; mi < 4; ++mi) {
    int rowb = m0 + wr + mi * 16 + fh * 4;
#pragma unroll
    for (int ni = 0; ni < 4; ++ni) {
      int col = n0 + wc + ni * 16 + fr;
      float bv = 0.f;
      if (bias && !BROW) bv = bias[col];
      float vals[4];
#pragma unroll
      for (int r = 0; r < 4; ++r) {
        int row = rowb + r;
        float v = acc[mi][ni][r];
        if (bias && BROW) bv = bias[row & 255];
        v += bv;
        if (ACT == 1) v = gelu_exact(v);
        if (res) v += res[(size_t)row * Nn + col];
        vals[r] = v;
      }
      if (EPI == 0) {
#pragma unroll
        for (int r = 0; r < 4; ++r)
          Cf[(size_t)(rowb + r) * Nn + col] = vals[r];
      } else if (EPI == 1) {
#pragma unroll
        for (int r = 0; r < 4; ++r)
          Cb[(size_t)(rowb + r) * Nn + col] = f2bf(vals[r]);
      } else if (EPI == 3) {
        if (col < 512) {
#pragma unroll
          for (int r = 0; r < 4; ++r)
            Cb[(size_t)(rowb + r) * Nn + col] = f2bf(vals[r]);
        } else {
          uint2 pk;
          pk.x = (uint)f2bf(vals[0]) | ((uint)f2bf(vals[1]) << 16);
          pk.y = (uint)f2bf(vals[2]) | ((uint)f2bf(vals[3]) << 16);
          ushort* vt = (ushort*)Cx;
          *(uint2*)&vt[((size_t)((rowb >> 10) * 256 + col - 512)) * 1024 +
                       (rowb & 1023)] = pk;
        }
      } else if (EPI == 4) {
#pragma unroll
        for (int r = 0; r < 4; ++r)
          Cb[(size_t)(rowb + r) * Nn + col] = f2bf(vals[r]);
        float4 v4 = {vals[0], vals[1], vals[2], vals[3]};
        float* x2p = (float*)Cx;
        *(float4*)&x2p[((size_t)((rowb >> 10) * 256 + col)) * 1024 +
                       (rowb & 1023)] = v4;
      }
    }
  }
}

// ---------------- MFMA flash attention ----------------
// qkv: [B,S,768] bf16 (q,k valid; v region unused). vt: [B*H,32,1024] bf16.
// Block = 4 waves x 16 q-rows of one (b,h). Swapped MFMAs, no barriers.
__global__ __launch_bounds__(256) void attn_mfma(const ushort* __restrict__ qkv,
                                                 const ushort* __restrict__ vt,
                                                 ushort* __restrict__ o) {
  __shared__ ushort P[4][16][72];
  int blk = blockIdx.x;  // [b(3)][h(3)][qt(4)]
  int qt = blk & 15, h = (blk >> 4) & 7, b = blk >> 7;
  int tid = threadIdx.x, wave = tid >> 6, lane = tid & 63;
  int lr = lane & 15, lg = lane >> 4;
  int q0 = qt * 64 + wave * 16;
  const ushort* qkbase = qkv + (size_t)b * S_ * 768 + h * 32;
  const ushort* vbase = vt + (size_t)(b * 256 + h * 32) * 1024;
  // Q B-frag: lane holds Q[q0+lr][lg*8 .. +7]
  bf16x8 qf = *(const bf16x8*)&qkbase[(size_t)(q0 + lr) * 768 + lg * 8];
  ushort* Prow = &P[wave][lr][0];
  f32x4 o0 = {0.f, 0.f, 0.f, 0.f}, o1 = {0.f, 0.f, 0.f, 0.f};
  float m = -1e30f, lsum = 0.f;
  const float scale = 0.17677669529663687f;  // 1/sqrt(32)
  const f32x4 zero = {0.f, 0.f, 0.f, 0.f};

  for (int t = 0; t < 16; ++t) {
    int k0 = t * 64;
    // S^T = K @ Q^T : lane holds scores for q=q0+lr, keys k0+s4*16+lg*4+r
    f32x4 s[4];
#pragma unroll
    for (int s4 = 0; s4 < 4; ++s4) {
      bf16x8 kf = *(const bf16x8*)&qkbase[(size_t)(k0 + s4 * 16 + lr) * 768 +
                                          256 + lg * 8];
      s[s4] = __builtin_amdgcn_mfma_f32_16x16x32_bf16(kf, qf, zero, 0, 0, 0);
    }
    // online softmax (raw-domain max, scale folded into exp arg)
    float mt = fmaxf(fmaxf(s[0][0], s[0][1]), fmaxf(s[0][2], s[0][3]));
    mt = fmaxf(mt, fmaxf(fmaxf(s[1][0], s[1][1]), fmaxf(s[1][2], s[1][3])));
    mt = fmaxf(mt, fmaxf(fmaxf(s[2][0], s[2][1]), fmaxf(s[2][2], s[2][3])));
    mt = fmaxf(mt, fmaxf(fmaxf(s[3][0], s[3][1]), fmaxf(s[3][2], s[3][3])));
    mt = fmaxf(mt, __shfl_xor(mt, 16));
    mt = fmaxf(mt, __shfl_xor(mt, 32));
    float mnew = fmaxf(m, mt * scale);
    float corr = __expf(m - mnew);
    m = mnew;
    o0 *= corr;
    o1 *= corr;
    lsum *= corr;
    float ps = 0.f;
#pragma unroll
    for (int s4 = 0; s4 < 4; ++s4) {
      float p0 = __expf(fmaf(s[s4][0], scale, -mnew));
      float p1 = __expf(fmaf(s[s4][1], scale, -mnew));
      float p2 = __expf(fmaf(s[s4][2], scale, -mnew));
      float p3 = __expf(fmaf(s[s4][3], scale, -mnew));
      ps += (p0 + p1) + (p2 + p3);
      uint2 pk;
      pk.x = (uint)f2bf_fast(p0) | ((uint)f2bf_fast(p1) << 16);
      pk.y = (uint)f2bf_fast(p2) | ((uint)f2bf_fast(p3) << 16);
      // P[q=lr][key-in-tile = s4*16 + lg*4 .. +3]
      *(uint2*)&Prow[s4 * 16 + lg * 4] = pk;
    }
    lsum += ps;
    // O^T += V^T @ P^T (wave-private LDS; HW keeps same-wave LDS order)
#pragma unroll
    for (int kc = 0; kc < 2; ++kc) {
      bf16x8 pf = *(const bf16x8*)&Prow[kc * 32 + lg * 8];
      bf16x8 v0f = *(const bf16x8*)&vbase[(size_t)lr * 1024 + k0 + kc * 32 +
                                          lg * 8];
      bf16x8 v1f = *(const bf16x8*)&vbase[(size_t)(16 + lr) * 1024 + k0 +
                                          kc * 32 + lg * 8];
      o0 = __builtin_amdgcn_mfma_f32_16x16x32_bf16(v0f, pf, o0, 0, 0, 0);
      o1 = __builtin_amdgcn_mfma_f32_16x16x32_bf16(v1f, pf, o1, 0, 0, 0);
    }
  }
  float lf = lsum + __shfl_xor(lsum, 16);
  lf += __shfl_xor(lf, 32);
  float inv = 1.f / lf;
  uint2 pk0, pk1;
  pk0.x = (uint)f2bf_fast(o0[0] * inv) | ((uint)f2bf_fast(o0[1] * inv) << 16);
  pk0.y = (uint)f2bf_fast(o0[2] * inv) | ((uint)f2bf_fast(o0[3] * inv) << 16);
  pk1.x = (uint)f2bf_fast(o1[0] * inv) | ((uint)f2bf_fast(o1[1] * inv) << 16);
  pk1.y = (uint)f2bf_fast(o1[2] * inv) | ((uint)f2bf_fast(o1[3] * inv) << 16);
  ushort* orow = &o[(size_t)((b << 10) + q0 + lr) * 256 + h * 32];
  *(uint2*)&orow[lg * 4] = pk0;       // d = lg*4+r
  *(uint2*)&orow[16 + lg * 4] = pk1;  // d = 16+lg*4+r
}

// ---------------- row softmax over 256, f32 in -> bf16 out ----------------
__global__ __launch_bounds__(256) void softmax256(const float* __restrict__ a,
                                                  ushort* __restrict__ ab) {
  __shared__ float s1s[4];
  int row = blockIdx.x;
  int j = threadIdx.x;
  float v = a[(size_t)row * 256 + j];
  float mx = v;
#pragma unroll
  for (int off = 32; off > 0; off >>= 1) mx = fmaxf(mx, __shfl_xor(mx, off));
  int wave = threadIdx.x >> 6;
  if ((threadIdx.x & 63) == 0) s1s[wave] = mx;
  __syncthreads();
  mx = fmaxf(fmaxf(s1s[0], s1s[1]), fmaxf(s1s[2], s1s[3]));
  __syncthreads();
  float e = __expf(v - mx);
  float ss = waveReduceSum(e);
  if ((threadIdx.x & 63) == 0) s1s[wave] = ss;
  __syncthreads();
  ss = s1s[0] + s1s[1] + s1s[2] + s1s[3];
  ab[(size_t)row * 256 + j] = f2bf(e / ss);
}

// ---------------- final: out = x2 + 0.1*den_c + 0.1*(dw3x3 + dw_b) ---------
__global__ __launch_bounds__(256) void final_kernel(
    const float* __restrict__ x2, const float* __restrict__ den_c,
    const float* __restrict__ dww, const float* __restrict__ dwb,
    float* __restrict__ out) {
  int idx = blockIdx.x * 256 + threadIdx.x;  // [b][c][y][x]
  int s = idx & 1023;
  int c = (idx >> 10) & 255;
  int b = idx >> 18;
  int y = s >> 5, x = s & 31;
  const float* plane = x2 + (size_t)(b * C_ + c) * S_;
  float lsum = 0.f;
#pragma unroll
  for (int dy = -1; dy <= 1; ++dy) {
    int yy = y + dy;
    if (yy < 0 || yy > 31) continue;
#pragma unroll
    for (int dx = -1; dx <= 1; ++dx) {
      int xx = x + dx;
      if (xx < 0 || xx > 31) continue;
      lsum += dww[c * 9 + (dy + 1) * 3 + (dx + 1)] * plane[yy * 32 + xx];
    }
  }
  lsum += dwb[c];
  out[idx] = x2[idx] + 0.1f * den_c[idx] + 0.1f * lsum;
}

// =====================================================================
extern "C" void kernel_launch(void* const* d_in, const int* in_sizes, int n_in,
                              void* d_out, int out_size, void* d_ws,
                              size_t ws_size, hipStream_t stream) {
  const float* x     = (const float*)d_in[0];
  const float* ln1_g = (const float*)d_in[1];
  const float* ln1_b = (const float*)d_in[2];
  const float* wqkv  = (const float*)d_in[3];
  const float* bqkv  = (const float*)d_in[4];
  const float* wo    = (const float*)d_in[5];
  const float* bo    = (const float*)d_in[6];
  const float* ln2_g = (const float*)d_in[7];
  const float* ln2_b = (const float*)d_in[8];
  const float* w1    = (const float*)d_in[9];
  const float* b1    = (const float*)d_in[10];
  const float* w2f   = (const float*)d_in[11];
  const float* b2    = (const float*)d_in[12];
  const float* c1_w  = (const float*)d_in[13];
  const float* c1_b  = (const float*)d_in[14];
  const float* c2_w  = (const float*)d_in[15];
  const float* c2_b  = (const float*)d_in[16];
  const float* c3_w  = (const float*)d_in[17];
  const float* c3_b  = (const float*)d_in[18];
  const float* dw_w  = (const float*)d_in[19];
  const float* dw_b  = (const float*)d_in[20];
  float* out = (float*)d_out;

  // workspace layout (f32 units), N = 2M elems; total ~8.75N = 70 MB
  float* ws = (float*)d_ws;
  const size_t N = NELT;
  float* t        = ws;                               // [0,N)
  ushort* qkv_bf  = (ushort*)(ws + N);                // [N,2.5N)
  ushort* v_t     = (ushort*)(ws + 2 * N + N / 2);    // [2.5N,3N)
  ushort* hdn_bf  = (ushort*)(ws + N);                // reuse [N,3N) after attn
  ushort* tn_bf   = (ushort*)(ws + 3 * N);            // [3N,3.5N)
  ushort* o_bf    = (ushort*)(ws + 3 * N + N / 2);    // [3.5N,4N)
  float* x2       = ws + 4 * N;                       // [4N,5N)
  float* den_c    = ws + 5 * N;                       // [5N,6N)
  ushort* t_bf    = (ushort*)(ws + 6 * N);            // [6N,6.5N)
  ushort* qf_c    = (ushort*)(ws + 6 * N + N / 2);    // [6.5N,7N)
  ushort* kf_c    = (ushort*)(ws + 7 * N);            // [7N,7.5N)
  ushort* vf      = (ushort*)(ws + 7 * N + N / 2);    // [7.5N,8N)
  float* amat     = ws + 8 * N;                       // [8N,8.25N)
  ushort* amat_bf = (ushort*)(ws + 8 * N + N / 4);    // [8.25N,8.375N)
  ushort* wbf     = (ushort*)(ws + 8 * N + N / 2);    // [8.5N,~8.735N)
  ushort* wqkv_bf = wbf;
  ushort* wo_bf   = wbf + 196608;
  ushort* w1_bf   = wbf + 262144;
  ushort* w2_bf   = wbf + 524288;
  ushort* c1_bf   = wbf + 786432;
  ushort* c2_bf   = wbf + 851968;
  ushort* c3_bf   = wbf + 917504;

  const long long PB = 262144;  // per-batch stride (1024*256)

  // 0. weights -> bf16
  cvt7<<<3840, 256, 0, stream>>>(wqkv, wo, w1, w2f, c1_w, c2_w, c3_w, wbf);
  // 1. transpose + LN1
  ln_kernel<1><<<M_, 256, 0, stream>>>(x, ln1_g, ln1_b, t, tn_bf);
  // 2. qkv: bf16 q,k + transposed v_t
  gemm_bf16<0, 3, 0><<<dim3(6, 64), 256, 0, stream>>>(
      tn_bf, wqkv_bf, bqkv, nullptr, nullptr, qkv_bf, v_t, M_, 768, 256, 0, 0,
      0, 0);
  // 3. MFMA flash attention -> o_bf
  attn_mfma<<<1024, 256, 0, stream>>>(qkv_bf, v_t, o_bf);
  // 4. t = t + o @ wo^T + bo
  gemm_bf16<0, 0, 0><<<dim3(2, 64), 256, 0, stream>>>(
      o_bf, wo_bf, bo, t, t, nullptr, nullptr, M_, 256, 256, 0, 0, 0, 0);
  // 5. tn = LN2(t)
  ln_kernel<0><<<M_, 256, 0, stream>>>(t, ln2_g, ln2_b, nullptr, tn_bf);
  // 6. hdn = gelu(tn @ w1^T + b1) -> bf16
  gemm_bf16<1, 1, 0><<<dim3(8, 64), 256, 0, stream>>>(
      tn_bf, w1_bf, b1, nullptr, nullptr, hdn_bf, nullptr, M_, HID_, 256, 0, 0,
      0, 0);
  // 7. t3 = t + hdn @ w2^T + b2 -> t_bf (bf16) + x2 (f32 transposed)
  gemm_bf16<0, 4, 0><<<dim3(2, 64), 256, 0, stream>>>(
      hdn_bf, w2_bf, b2, t, nullptr, t_bf, x2, M_, 256, HID_, 0, 0, 0, 0);
  // 8a. qf_c/kf_c [b,c,s] = cN_w @ t3_b^T + cN_b
  gemm_bf16<0, 1, 1><<<dim3(8, 16), 256, 0, stream>>>(
      c1_bf, t_bf, c1_b, nullptr, nullptr, qf_c, nullptr, 2048, 1024, 256, 256,
      0, 256, PB);
  gemm_bf16<0, 1, 1><<<dim3(8, 16), 256, 0, stream>>>(
      c2_bf, t_bf, c2_b, nullptr, nullptr, kf_c, nullptr, 2048, 1024, 256, 256,
      0, 256, PB);
  // 8b. vf [b,s,c] = t3 @ c3_w^T + c3_b
  gemm_bf16<0, 1, 0><<<dim3(2, 64), 256, 0, stream>>>(
      t_bf, c3_bf, c3_b, nullptr, nullptr, vf, nullptr, M_, 256, 256, 0, 0, 0,
      0);
  // 10. amat[b,i,j] = qf_c[b,i,:] . kf_c[b,j,:]
  gemm_bf16<0, 0, 0><<<dim3(2, 16), 256, 0, stream>>>(
      qf_c, kf_c, nullptr, nullptr, amat, nullptr, nullptr, 2048, 256, 1024,
      256, PB, 256, PB);
  // 11. softmax rows -> bf16
  softmax256<<<2048, 256, 0, stream>>>(amat, amat_bf);
  // 12. den_c[b,c,s] = a_b @ vf_b^T
  gemm_bf16<0, 0, 0><<<dim3(8, 16), 256, 0, stream>>>(
      amat_bf, vf, nullptr, nullptr, den_c, nullptr, nullptr, 2048, 1024, 256,
      0, 0, 256, PB);
  // 13. final combine + depthwise conv
  final_kernel<<<8192, 256, 0, stream>>>(x2, den_c, dw_w, dw_b, out);
}

// Round 5
// 233.671 us; speedup vs baseline: 5.0579x; 1.2484x over previous
//
#include <hip/hip_runtime.h>
#include <hip/hip_bf16.h>
#include <math.h>

#define B_   8
#define C_   256
#define S_   1024
#define M_   8192    // B_*S_
#define HID_ 1024
#define NELT 2097152 // B_*C_*S_

typedef __attribute__((ext_vector_type(4))) float f32x4;
typedef __attribute__((ext_vector_type(8))) short bf16x8;

__device__ __forceinline__ ushort f2bf(float f) {
  union { float f; unsigned u; } c; c.f = f;
  unsigned u = c.u;
  return (ushort)((u + 0x7fff + ((u >> 16) & 1)) >> 16);
}
__device__ __forceinline__ ushort f2bf_fast(float f) {
  __hip_bfloat16 h = __float2bfloat16(f);
  return *reinterpret_cast<ushort*>(&h);
}

// ---------------- reduction helpers ----------------
__device__ __forceinline__ float waveReduceSum(float v) {
#pragma unroll
  for (int off = 32; off > 0; off >>= 1) v += __shfl_xor(v, off);
  return v;
}

// ---------------- LN1 fused with transpose, LDS-tiled (coalesced) ----------
__global__ __launch_bounds__(256) void ln1_tiled(const float* __restrict__ x,
                                                 const float* __restrict__ g,
                                                 const float* __restrict__ bta,
                                                 float* __restrict__ t,
                                                 ushort* __restrict__ tn) {
  __shared__ float T[32][257];
  __shared__ float mus[32], rss[32];
  int blk = blockIdx.x;
  int st = blk & 31, b = blk >> 5;
  int tid = threadIdx.x;
  int s0 = st * 32;
  // phase1: coalesced load of x[b][c][s0..s0+31]
  for (int i = tid; i < 2048; i += 256) {
    int c = i >> 3, j4 = (i & 7) * 4;
    float4 v = *(const float4*)&x[((size_t)(b * 256 + c) << 10) + s0 + j4];
    T[j4 + 0][c] = v.x; T[j4 + 1][c] = v.y;
    T[j4 + 2][c] = v.z; T[j4 + 3][c] = v.w;
  }
  __syncthreads();
  // phase2: per-row stats (8 threads per row)
  {
    int j = tid >> 3, e = tid & 7;
    float s1 = 0.f, s2 = 0.f;
#pragma unroll
    for (int cc = 0; cc < 32; ++cc) {
      float v = T[j][e + cc * 8];
      s1 += v; s2 += v * v;
    }
    s1 += __shfl_xor(s1, 1); s2 += __shfl_xor(s2, 1);
    s1 += __shfl_xor(s1, 2); s2 += __shfl_xor(s2, 2);
    s1 += __shfl_xor(s1, 4); s2 += __shfl_xor(s2, 4);
    if (e == 0) {
      float mu = s1 * (1.0f / 256.0f);
      float var = s2 * (1.0f / 256.0f) - mu * mu;
      mus[j] = mu;
      rss[j] = rsqrtf(var + 1e-5f);
    }
  }
  __syncthreads();
  // phase3: coalesced writes of t (f32) and tn (bf16)
  for (int i = tid; i < 4096; i += 256) {
    int jj = i >> 7, c = (i & 127) * 2;
    float mu = mus[jj], rs = rss[jj];
    float v0 = T[jj][c], v1 = T[jj][c + 1];
    size_t row = (size_t)(b * 1024 + s0 + jj) * 256 + c;
    float2 tv = {v0, v1};
    *(float2*)&t[row] = tv;
    uint pk = (uint)f2bf((v0 - mu) * rs * g[c] + bta[c]) |
              ((uint)f2bf((v1 - mu) * rs * g[c + 1] + bta[c + 1]) << 16);
    *(uint*)&tn[row] = pk;
  }
}

// ---------------- LayerNorm (row-major input) ----------------
__global__ __launch_bounds__(256) void ln_kernel(const float* __restrict__ in,
                                                 const float* __restrict__ g,
                                                 const float* __restrict__ bta,
                                                 ushort* __restrict__ tn) {
  __shared__ float s1s[4], s2s[4];
  int row = blockIdx.x;
  int c = threadIdx.x;
  float v = in[(size_t)row * C_ + c];
  float s1 = waveReduceSum(v);
  float s2 = waveReduceSum(v * v);
  int wave = threadIdx.x >> 6;
  if ((threadIdx.x & 63) == 0) { s1s[wave] = s1; s2s[wave] = s2; }
  __syncthreads();
  s1 = s1s[0] + s1s[1] + s1s[2] + s1s[3];
  s2 = s2s[0] + s2s[1] + s2s[2] + s2s[3];
  float mu = s1 * (1.0f / 256.0f);
  float var = s2 * (1.0f / 256.0f) - mu * mu;
  float rs = rsqrtf(var + 1e-5f);
  tn[(size_t)row * C_ + c] = f2bf((v - mu) * rs * g[c] + bta[c]);
}

// ---------------- weight convert f32 -> bf16 (all 7 weights) ----------------
__global__ __launch_bounds__(256) void cvt7(
    const float* __restrict__ s0, const float* __restrict__ s1,
    const float* __restrict__ s2, const float* __restrict__ s3,
    const float* __restrict__ s4, const float* __restrict__ s5,
    const float* __restrict__ s6, ushort* __restrict__ dst) {
  int i = blockIdx.x * 256 + threadIdx.x;
  const float* s; int off;
  if (i < 196608)      { s = s0; off = 0; }
  else if (i < 262144) { s = s1; off = 196608; }
  else if (i < 524288) { s = s2; off = 262144; }
  else if (i < 786432) { s = s3; off = 524288; }
  else if (i < 851968) { s = s4; off = 786432; }
  else if (i < 917504) { s = s5; off = 851968; }
  else                 { s = s6; off = 917504; }
  dst[i] = f2bf(s[i - off]);
}

__device__ __forceinline__ int swzr(int r) { return (r ^ (r >> 2)) & 3; }
__device__ __forceinline__ float gelu_exact(float v) {
  return 0.5f * v * (1.0f + erff(v * 0.70710678118654752f));
}

// ---------------- 128x128 bf16 MFMA GEMM ----------------
// EPI: 0 = f32 out, 1 = bf16 out, 3 = qkv (bf16 q/k + transposed v_t),
//      4 = bf16 out + f32 transposed x2
template <int ACT, int EPI, int BROW>
__global__ __launch_bounds__(256) void gemm_bf16(
    const ushort* __restrict__ A, const ushort* __restrict__ W,
    const float* __restrict__ bias, const float* __restrict__ res,
    float* __restrict__ Cf, ushort* __restrict__ Cb, void* __restrict__ Cx,
    int M, int Nn, int K,
    int a_rpb, long long a_bstride, int w_rpb, long long w_bstride) {
  __shared__ ushort As[4096];  // [128][32]
  __shared__ ushort Bs[4096];
  int tid = threadIdx.x;
  int lane = tid & 63, wave = tid >> 6;
  int m0 = blockIdx.y * 128, n0 = blockIdx.x * 128;
  const ushort* Ab;
  if (a_rpb)
    Ab = A + (size_t)(m0 / a_rpb) * a_bstride + (size_t)(m0 % a_rpb) * K;
  else
    Ab = A + (size_t)m0 * K;
  const ushort* Wb = W + (size_t)n0 * K;
  if (w_rpb) Wb += (size_t)(m0 / w_rpb) * w_bstride;
  int srow = tid >> 2;
  int sch = tid & 3;
  int fr = lane & 15, fh = lane >> 4;
  int wr = (wave >> 1) * 64, wc = (wave & 1) * 64;
  f32x4 acc[4][4];
#pragma unroll
  for (int i = 0; i < 4; ++i)
#pragma unroll
    for (int j = 0; j < 4; ++j) acc[i][j] = (f32x4){0.f, 0.f, 0.f, 0.f};

  int sw0 = (sch ^ swzr(srow)) * 8;
  int sw1 = (sch ^ swzr(srow + 64)) * 8;
  for (int k0 = 0; k0 < K; k0 += 32) {
    uint4 a0 = *(const uint4*)&Ab[(size_t)srow * K + k0 + sch * 8];
    uint4 a1 = *(const uint4*)&Ab[(size_t)(srow + 64) * K + k0 + sch * 8];
    uint4 b0 = *(const uint4*)&Wb[(size_t)srow * K + k0 + sch * 8];
    uint4 b1 = *(const uint4*)&Wb[(size_t)(srow + 64) * K + k0 + sch * 8];
    __syncthreads();
    *(uint4*)&As[srow * 32 + sw0] = a0;
    *(uint4*)&As[(srow + 64) * 32 + sw1] = a1;
    *(uint4*)&Bs[srow * 32 + sw0] = b0;
    *(uint4*)&Bs[(srow + 64) * 32 + sw1] = b1;
    __syncthreads();
    bf16x8 af[4], bfv[4];
#pragma unroll
    for (int mi = 0; mi < 4; ++mi) {
      int r = wr + mi * 16 + fr;
      af[mi] = *(const bf16x8*)&As[r * 32 + ((fh ^ swzr(r)) * 8)];
    }
#pragma unroll
    for (int ni = 0; ni < 4; ++ni) {
      int r = wc + ni * 16 + fr;
      bfv[ni] = *(const bf16x8*)&Bs[r * 32 + ((fh ^ swzr(r)) * 8)];
    }
#pragma unroll
    for (int mi = 0; mi < 4; ++mi)
#pragma unroll
      for (int ni = 0; ni < 4; ++ni)
        acc[mi][ni] = __builtin_amdgcn_mfma_f32_16x16x32_bf16(
            af[mi], bfv[ni], acc[mi][ni], 0, 0, 0);
  }
#pragma unroll
  for (int mi = 0; mi < 4; ++mi) {
    int rowb = m0 + wr + mi * 16 + fh * 4;
#pragma unroll
    for (int ni = 0; ni < 4; ++ni) {
      int col = n0 + wc + ni * 16 + fr;
      float bv = 0.f;
      if (bias && !BROW) bv = bias[col];
      float vals[4];
#pragma unroll
      for (int r = 0; r < 4; ++r) {
        int row = rowb + r;
        float v = acc[mi][ni][r];
        if (bias && BROW) bv = bias[row & 255];
        v += bv;
        if (ACT == 1) v = gelu_exact(v);
        if (res) v += res[(size_t)row * Nn + col];
        vals[r] = v;
      }
      if (EPI == 0) {
#pragma unroll
        for (int r = 0; r < 4; ++r)
          Cf[(size_t)(rowb + r) * Nn + col] = vals[r];
      } else if (EPI == 1) {
#pragma unroll
        for (int r = 0; r < 4; ++r)
          Cb[(size_t)(rowb + r) * Nn + col] = f2bf(vals[r]);
      } else if (EPI == 3) {
        if (col < 512) {
#pragma unroll
          for (int r = 0; r < 4; ++r)
            Cb[(size_t)(rowb + r) * Nn + col] = f2bf(vals[r]);
        } else {
          uint2 pk;
          pk.x = (uint)f2bf(vals[0]) | ((uint)f2bf(vals[1]) << 16);
          pk.y = (uint)f2bf(vals[2]) | ((uint)f2bf(vals[3]) << 16);
          ushort* vt = (ushort*)Cx;
          *(uint2*)&vt[((size_t)((rowb >> 10) * 256 + col - 512)) * 1024 +
                       (rowb & 1023)] = pk;
        }
      } else if (EPI == 4) {
#pragma unroll
        for (int r = 0; r < 4; ++r)
          Cb[(size_t)(rowb + r) * Nn + col] = f2bf(vals[r]);
        float4 v4 = {vals[0], vals[1], vals[2], vals[3]};
        float* x2p = (float*)Cx;
        *(float4*)&x2p[((size_t)((rowb >> 10) * 256 + col)) * 1024 +
                       (rowb & 1023)] = v4;
      }
    }
  }
}

// ---------------- (MF*64)x64 bf16 MFMA GEMM (better grid coverage) ---------
// MF=2: 128x64 tile, wave = 32 rows; MF=1: 64x64 tile, wave = 16 rows.
template <int MF, int ACT, int EPI, int BROW>
__global__ __launch_bounds__(256) void gemm_n64(
    const ushort* __restrict__ A, const ushort* __restrict__ W,
    const float* __restrict__ bias, const float* __restrict__ res,
    float* __restrict__ Cf, ushort* __restrict__ Cb, void* __restrict__ Cx,
    int M, int Nn, int K,
    int a_rpb, long long a_bstride, int w_rpb, long long w_bstride) {
  __shared__ ushort As[MF * 2048];
  __shared__ ushort Bs[2048];
  int tid = threadIdx.x;
  int lane = tid & 63, wave = tid >> 6;
  int m0 = blockIdx.y * (MF * 64), n0 = blockIdx.x * 64;
  const ushort* Ab;
  if (a_rpb)
    Ab = A + (size_t)(m0 / a_rpb) * a_bstride + (size_t)(m0 % a_rpb) * K;
  else
    Ab = A + (size_t)m0 * K;
  const ushort* Wb = W + (size_t)n0 * K;
  if (w_rpb) Wb += (size_t)(m0 / w_rpb) * w_bstride;
  int srow = tid >> 2;
  int sch = tid & 3;
  int fr = lane & 15, fh = lane >> 4;
  int wr = wave * (MF * 16);
  f32x4 acc[MF][4];
#pragma unroll
  for (int i = 0; i < MF; ++i)
#pragma unroll
    for (int j = 0; j < 4; ++j) acc[i][j] = (f32x4){0.f, 0.f, 0.f, 0.f};

  int sw0 = (sch ^ swzr(srow)) * 8;
  int sw1 = (sch ^ swzr(srow + 64)) * 8;
  for (int k0 = 0; k0 < K; k0 += 32) {
    uint4 a0 = *(const uint4*)&Ab[(size_t)srow * K + k0 + sch * 8];
    uint4 a1;
    if (MF == 2) a1 = *(const uint4*)&Ab[(size_t)(srow + 64) * K + k0 + sch * 8];
    uint4 b0 = *(const uint4*)&Wb[(size_t)srow * K + k0 + sch * 8];
    __syncthreads();
    *(uint4*)&As[srow * 32 + sw0] = a0;
    if (MF == 2) *(uint4*)&As[(srow + 64) * 32 + sw1] = a1;
    *(uint4*)&Bs[srow * 32 + sw0] = b0;
    __syncthreads();
    bf16x8 af[MF], bfv[4];
#pragma unroll
    for (int mi = 0; mi < MF; ++mi) {
      int r = wr + mi * 16 + fr;
      af[mi] = *(const bf16x8*)&As[r * 32 + ((fh ^ swzr(r)) * 8)];
    }
#pragma unroll
    for (int ni = 0; ni < 4; ++ni) {
      int r = ni * 16 + fr;
      bfv[ni] = *(const bf16x8*)&Bs[r * 32 + ((fh ^ swzr(r)) * 8)];
    }
#pragma unroll
    for (int mi = 0; mi < MF; ++mi)
#pragma unroll
      for (int ni = 0; ni < 4; ++ni)
        acc[mi][ni] = __builtin_amdgcn_mfma_f32_16x16x32_bf16(
            af[mi], bfv[ni], acc[mi][ni], 0, 0, 0);
  }
#pragma unroll
  for (int mi = 0; mi < MF; ++mi) {
    int rowb = m0 + wr + mi * 16 + fh * 4;
#pragma unroll
    for (int ni = 0; ni < 4; ++ni) {
      int col = n0 + ni * 16 + fr;
      float bv = 0.f;
      if (bias && !BROW) bv = bias[col];
      float vals[4];
#pragma unroll
      for (int r = 0; r < 4; ++r) {
        int row = rowb + r;
        float v = acc[mi][ni][r];
        if (bias && BROW) bv = bias[row & 255];
        v += bv;
        if (ACT == 1) v = gelu_exact(v);
        if (res) v += res[(size_t)row * Nn + col];
        vals[r] = v;
      }
      if (EPI == 0) {
#pragma unroll
        for (int r = 0; r < 4; ++r)
          Cf[(size_t)(rowb + r) * Nn + col] = vals[r];
      } else if (EPI == 1) {
#pragma unroll
        for (int r = 0; r < 4; ++r)
          Cb[(size_t)(rowb + r) * Nn + col] = f2bf(vals[r]);
      } else if (EPI == 4) {
#pragma unroll
        for (int r = 0; r < 4; ++r)
          Cb[(size_t)(rowb + r) * Nn + col] = f2bf(vals[r]);
        float4 v4 = {vals[0], vals[1], vals[2], vals[3]};
        float* x2p = (float*)Cx;
        *(float4*)&x2p[((size_t)((rowb >> 10) * 256 + col)) * 1024 +
                       (rowb & 1023)] = v4;
      }
    }
  }
}

// ---------------- MFMA flash attention v2 (128-key tiles) ----------------
// qkv: [B,S,768] bf16 (q,k). vt: [B*H,32,1024] bf16.
// Block = 4 waves x 16 q-rows; 8 iterations of 128 keys. No barriers.
__global__ __launch_bounds__(256, 4) void attn_mfma(const ushort* __restrict__ qkv,
                                                    const ushort* __restrict__ vt,
                                                    ushort* __restrict__ o) {
  __shared__ ushort P[4][16][136];  // 128 keys + pad, XOR-swizzled in 8B units
  int blk = blockIdx.x;  // [b(3)][h(3)][qt(4)]
  int qt = blk & 15, h = (blk >> 4) & 7, b = blk >> 7;
  int tid = threadIdx.x, wave = tid >> 6, lane = tid & 63;
  int lr = lane & 15, lg = lane >> 4;
  int q0 = qt * 64 + wave * 16;
  const ushort* qkbase = qkv + (size_t)b * S_ * 768 + h * 32;
  const ushort* vbase = vt + (size_t)(b * 256 + h * 32) * 1024;
  bf16x8 qf = *(const bf16x8*)&qkbase[(size_t)(q0 + lr) * 768 + lg * 8];
  ushort* Prow = &P[wave][lr][0];
  int xs = lr & 7;  // XOR swizzle for 8B units
  f32x4 o0 = {0.f, 0.f, 0.f, 0.f}, o1 = {0.f, 0.f, 0.f, 0.f};
  float m = -1e30f, lsum = 0.f;
  const float scale = 0.17677669529663687f;  // 1/sqrt(32)
  const f32x4 zero = {0.f, 0.f, 0.f, 0.f};

  for (int t = 0; t < 8; ++t) {
    int k0 = t * 128;
    // hoist ALL loads for this iteration (latency hides under QK + softmax)
    bf16x8 kf[8];
#pragma unroll
    for (int i = 0; i < 8; ++i)
      kf[i] = *(const bf16x8*)&qkbase[(size_t)(k0 + i * 16 + lr) * 768 + 256 +
                                      lg * 8];
    bf16x8 v0f[4], v1f[4];
#pragma unroll
    for (int kc = 0; kc < 4; ++kc) {
      v0f[kc] = *(const bf16x8*)&vbase[(size_t)lr * 1024 + k0 + kc * 32 +
                                       lg * 8];
      v1f[kc] = *(const bf16x8*)&vbase[(size_t)(16 + lr) * 1024 + k0 +
                                       kc * 32 + lg * 8];
    }
    // S^T = K @ Q^T : lane holds scores for q=q0+lr, keys k0+i*16+lg*4+r
    f32x4 s[8];
    __builtin_amdgcn_s_setprio(1);
#pragma unroll
    for (int i = 0; i < 8; ++i)
      s[i] = __builtin_amdgcn_mfma_f32_16x16x32_bf16(kf[i], qf, zero, 0, 0, 0);
    __builtin_amdgcn_s_setprio(0);
    // online softmax over 128 keys
    float mt = -1e30f;
#pragma unroll
    for (int i = 0; i < 8; ++i)
      mt = fmaxf(mt, fmaxf(fmaxf(s[i][0], s[i][1]), fmaxf(s[i][2], s[i][3])));
    mt = fmaxf(mt, __shfl_xor(mt, 16));
    mt = fmaxf(mt, __shfl_xor(mt, 32));
    float mnew = fmaxf(m, mt * scale);
    float corr = __expf(m - mnew);
    m = mnew;
    o0 *= corr;
    o1 *= corr;
    lsum *= corr;
    float ps = 0.f;
#pragma unroll
    for (int i = 0; i < 8; ++i) {
      float p0 = __expf(fmaf(s[i][0], scale, -mnew));
      float p1 = __expf(fmaf(s[i][1], scale, -mnew));
      float p2 = __expf(fmaf(s[i][2], scale, -mnew));
      float p3 = __expf(fmaf(s[i][3], scale, -mnew));
      ps += (p0 + p1) + (p2 + p3);
      uint2 pk;
      pk.x = (uint)f2bf_fast(p0) | ((uint)f2bf_fast(p1) << 16);
      pk.y = (uint)f2bf_fast(p2) | ((uint)f2bf_fast(p3) << 16);
      // unit index (i*4+lg) XOR'd per-row -> ~conflict-free
      *(uint2*)&Prow[((i ^ xs) * 16) + lg * 4] = pk;
    }
    lsum += ps;
    // O^T += V^T @ P^T (wave-private LDS exchange, no barrier)
    __builtin_amdgcn_s_setprio(1);
#pragma unroll
    for (int kc = 0; kc < 2; ++kc) {
#pragma unroll
      for (int kh = 0; kh < 2; ++kh) {
        int kc4 = kc * 2 + kh;
        bf16x8 pf =
            *(const bf16x8*)&Prow[((kc4 * 8 + lg * 2) ^ (xs * 4)) * 4];
        o0 = __builtin_amdgcn_mfma_f32_16x16x32_bf16(v0f[kc4], pf, o0, 0, 0, 0);
        o1 = __builtin_amdgcn_mfma_f32_16x16x32_bf16(v1f[kc4], pf, o1, 0, 0, 0);
      }
    }
    __builtin_amdgcn_s_setprio(0);
  }
  float lf = lsum + __shfl_xor(lsum, 16);
  lf += __shfl_xor(lf, 32);
  float inv = 1.f / lf;
  uint2 pk0, pk1;
  pk0.x = (uint)f2bf_fast(o0[0] * inv) | ((uint)f2bf_fast(o0[1] * inv) << 16);
  pk0.y = (uint)f2bf_fast(o0[2] * inv) | ((uint)f2bf_fast(o0[3] * inv) << 16);
  pk1.x = (uint)f2bf_fast(o1[0] * inv) | ((uint)f2bf_fast(o1[1] * inv) << 16);
  pk1.y = (uint)f2bf_fast(o1[2] * inv) | ((uint)f2bf_fast(o1[3] * inv) << 16);
  ushort* orow = &o[(size_t)((b << 10) + q0 + lr) * 256 + h * 32];
  *(uint2*)&orow[lg * 4] = pk0;
  *(uint2*)&orow[16 + lg * 4] = pk1;
}

// ---------------- row softmax over 256, f32 in -> bf16 out ----------------
__global__ __launch_bounds__(256) void softmax256(const float* __restrict__ a,
                                                  ushort* __restrict__ ab) {
  __shared__ float s1s[4];
  int row = blockIdx.x;
  int j = threadIdx.x;
  float v = a[(size_t)row * 256 + j];
  float mx = v;
#pragma unroll
  for (int off = 32; off > 0; off >>= 1) mx = fmaxf(mx, __shfl_xor(mx, off));
  int wave = threadIdx.x >> 6;
  if ((threadIdx.x & 63) == 0) s1s[wave] = mx;
  __syncthreads();
  mx = fmaxf(fmaxf(s1s[0], s1s[1]), fmaxf(s1s[2], s1s[3]));
  __syncthreads();
  float e = __expf(v - mx);
  float ss = waveReduceSum(e);
  if ((threadIdx.x & 63) == 0) s1s[wave] = ss;
  __syncthreads();
  ss = s1s[0] + s1s[1] + s1s[2] + s1s[3];
  ab[(size_t)row * 256 + j] = f2bf(e / ss);
}

// ---------------- final: out = x2 + 0.1*den_c + 0.1*(dw3x3 + dw_b) ---------
__global__ __launch_bounds__(256) void final_kernel(
    const float* __restrict__ x2, const float* __restrict__ den_c,
    const float* __restrict__ dww, const float* __restrict__ dwb,
    float* __restrict__ out) {
  int idx = blockIdx.x * 256 + threadIdx.x;  // [b][c][y][x]
  int s = idx & 1023;
  int c = (idx >> 10) & 255;
  int b = idx >> 18;
  int y = s >> 5, x = s & 31;
  const float* plane = x2 + (size_t)(b * C_ + c) * S_;
  float lsum = 0.f;
#pragma unroll
  for (int dy = -1; dy <= 1; ++dy) {
    int yy = y + dy;
    if (yy < 0 || yy > 31) continue;
#pragma unroll
    for (int dx = -1; dx <= 1; ++dx) {
      int xx = x + dx;
      if (xx < 0 || xx > 31) continue;
      lsum += dww[c * 9 + (dy + 1) * 3 + (dx + 1)] * plane[yy * 32 + xx];
    }
  }
  lsum += dwb[c];
  out[idx] = x2[idx] + 0.1f * den_c[idx] + 0.1f * lsum;
}

// =====================================================================
extern "C" void kernel_launch(void* const* d_in, const int* in_sizes, int n_in,
                              void* d_out, int out_size, void* d_ws,
                              size_t ws_size, hipStream_t stream) {
  const float* x     = (const float*)d_in[0];
  const float* ln1_g = (const float*)d_in[1];
  const float* ln1_b = (const float*)d_in[2];
  const float* wqkv  = (const float*)d_in[3];
  const float* bqkv  = (const float*)d_in[4];
  const float* wo    = (const float*)d_in[5];
  const float* bo    = (const float*)d_in[6];
  const float* ln2_g = (const float*)d_in[7];
  const float* ln2_b = (const float*)d_in[8];
  const float* w1    = (const float*)d_in[9];
  const float* b1    = (const float*)d_in[10];
  const float* w2f   = (const float*)d_in[11];
  const float* b2    = (const float*)d_in[12];
  const float* c1_w  = (const float*)d_in[13];
  const float* c1_b  = (const float*)d_in[14];
  const float* c2_w  = (const float*)d_in[15];
  const float* c2_b  = (const float*)d_in[16];
  const float* c3_w  = (const float*)d_in[17];
  const float* c3_b  = (const float*)d_in[18];
  const float* dw_w  = (const float*)d_in[19];
  const float* dw_b  = (const float*)d_in[20];
  float* out = (float*)d_out;

  float* ws = (float*)d_ws;
  const size_t N = NELT;
  float* t        = ws;                               // [0,N)
  ushort* qkv_bf  = (ushort*)(ws + N);                // [N,2.5N)
  ushort* v_t     = (ushort*)(ws + 2 * N + N / 2);    // [2.5N,3N)
  ushort* hdn_bf  = (ushort*)(ws + N);                // reuse after attn
  ushort* tn_bf   = (ushort*)(ws + 3 * N);            // [3N,3.5N)
  ushort* o_bf    = (ushort*)(ws + 3 * N + N / 2);    // [3.5N,4N)
  float* x2       = ws + 4 * N;                       // [4N,5N)
  float* den_c    = ws + 5 * N;                       // [5N,6N)
  ushort* t_bf    = (ushort*)(ws + 6 * N);            // [6N,6.5N)
  ushort* qf_c    = (ushort*)(ws + 6 * N + N / 2);    // [6.5N,7N)
  ushort* kf_c    = (ushort*)(ws + 7 * N);            // [7N,7.5N)
  ushort* vf      = (ushort*)(ws + 7 * N + N / 2);    // [7.5N,8N)
  float* amat     = ws + 8 * N;                       // [8N,8.25N)
  ushort* amat_bf = (ushort*)(ws + 8 * N + N / 4);    // [8.25N,8.375N)
  ushort* wbf     = (ushort*)(ws + 8 * N + N / 2);    // weights bf16
  ushort* wqkv_bf = wbf;
  ushort* wo_bf   = wbf + 196608;
  ushort* w1_bf   = wbf + 262144;
  ushort* w2_bf   = wbf + 524288;
  ushort* c1_bf   = wbf + 786432;
  ushort* c2_bf   = wbf + 851968;
  ushort* c3_bf   = wbf + 917504;

  const long long PB = 262144;  // per-batch stride (1024*256)

  // 0. weights -> bf16
  cvt7<<<3840, 256, 0, stream>>>(wqkv, wo, w1, w2f, c1_w, c2_w, c3_w, wbf);
  // 1. transpose + LN1 (coalesced, LDS-tiled)
  ln1_tiled<<<256, 256, 0, stream>>>(x, ln1_g, ln1_b, t, tn_bf);
  // 2. qkv: bf16 q,k + transposed v_t
  gemm_bf16<0, 3, 0><<<dim3(6, 64), 256, 0, stream>>>(
      tn_bf, wqkv_bf, bqkv, nullptr, nullptr, qkv_bf, v_t, M_, 768, 256, 0, 0,
      0, 0);
  // 3. MFMA flash attention -> o_bf
  attn_mfma<<<1024, 256, 0, stream>>>(qkv_bf, v_t, o_bf);
  // 4. t = t + o @ wo^T + bo
  gemm_n64<2, 0, 0, 0><<<dim3(4, 64), 256, 0, stream>>>(
      o_bf, wo_bf, bo, t, t, nullptr, nullptr, M_, 256, 256, 0, 0, 0, 0);
  // 5. tn = LN2(t)
  ln_kernel<<<M_, 256, 0, stream>>>(t, ln2_g, ln2_b, tn_bf);
  // 6. hdn = gelu(tn @ w1^T + b1) -> bf16
  gemm_bf16<1, 1, 0><<<dim3(8, 64), 256, 0, stream>>>(
      tn_bf, w1_bf, b1, nullptr, nullptr, hdn_bf, nullptr, M_, HID_, 256, 0, 0,
      0, 0);
  // 7. t3 = t + hdn @ w2^T + b2 -> t_bf (bf16) + x2 (f32 transposed)
  gemm_n64<2, 0, 4, 0><<<dim3(4, 64), 256, 0, stream>>>(
      hdn_bf, w2_bf, b2, t, nullptr, t_bf, x2, M_, 256, HID_, 0, 0, 0, 0);
  // 8a. qf_c/kf_c [b,c,s] = cN_w @ t3_b^T + cN_b
  gemm_n64<2, 0, 1, 1><<<dim3(16, 16), 256, 0, stream>>>(
      c1_bf, t_bf, c1_b, nullptr, nullptr, qf_c, nullptr, 2048, 1024, 256, 256,
      0, 256, PB);
  gemm_n64<2, 0, 1, 1><<<dim3(16, 16), 256, 0, stream>>>(
      c2_bf, t_bf, c2_b, nullptr, nullptr, kf_c, nullptr, 2048, 1024, 256, 256,
      0, 256, PB);
  // 8b. vf [b,s,c] = t3 @ c3_w^T + c3_b
  gemm_n64<2, 0, 1, 0><<<dim3(4, 64), 256, 0, stream>>>(
      t_bf, c3_bf, c3_b, nullptr, nullptr, vf, nullptr, M_, 256, 256, 0, 0, 0,
      0);
  // 10. amat[b,i,j] = qf_c[b,i,:] . kf_c[b,j,:]
  gemm_n64<1, 0, 0, 0><<<dim3(4, 32), 256, 0, stream>>>(
      qf_c, kf_c, nullptr, nullptr, amat, nullptr, nullptr, 2048, 256, 1024,
      256, PB, 256, PB);
  // 11. softmax rows -> bf16
  softmax256<<<2048, 256, 0, stream>>>(amat, amat_bf);
  // 12. den_c[b,c,s] = a_b @ vf_b^T
  gemm_n64<2, 0, 0, 0><<<dim3(16, 16), 256, 0, stream>>>(
      amat_bf, vf, nullptr, nullptr, den_c, nullptr, nullptr, 2048, 1024, 256,
      0, 0, 256, PB);
  // 13. final combine + depthwise conv
  final_kernel<<<8192, 256, 0, stream>>>(x2, den_c, dw_w, dw_b, out);
}